// Round 1
// baseline (1816.804 us; speedup 1.0000x reference)
//
#include <hip/hip_runtime.h>

#define TILE_M 64
#define TILE_N 64
#define TILE_K 32

// Tiled GEMM body. Computes C[m,n] (+bias[n]) for one 64x64 tile.
//  B_NT = true :  C[m,n] = sum_k A[m,k] * B[n,k]   (B row-major over k, "NT")
//  B_NT = false:  C[m,n] = sum_k A[m,k] * B[k,n]   (B row-major over n, "NN")
// 256 threads, each computes a 4x4 micro-tile. K staged transposed in LDS so
// the inner loop is 2x ds_read_b128 + 16x v_fma_f32 per kk.
template <bool B_NT, bool HAS_BIAS>
__device__ __forceinline__ void gemm_body(const float* __restrict__ A,
                                          const float* __restrict__ Bm,
                                          const float* __restrict__ bias,
                                          float* __restrict__ C,
                                          int lda, int ldb, int ldc, int Kdim) {
  __shared__ float As[TILE_K][TILE_M + 4];  // +4 pad: keeps 16B align, breaks write conflicts
  __shared__ float Bs[TILE_K][TILE_N + 4];

  const int tid = threadIdx.x;
  const int tx = tid & 15;   // output column group
  const int ty = tid >> 4;   // output row group
  const int m0 = blockIdx.y * TILE_M;
  const int n0 = blockIdx.x * TILE_N;

  // Staging indices for transposed (NT) tiles: 64 rows x 32 k, float4 along k.
  const int am = tid >> 3;         // 0..31 (row; +32 for second half)
  const int ak = (tid & 7) << 2;   // 0,4,...,28 (k offset)
  // Staging indices for NN B tile: 32 k-rows x 64 n, float4 along n.
  const int bk_ = tid >> 4;        // 0..15 (k row; +16 for second half)
  const int bn  = (tid & 15) << 2; // 0..60 (n offset)

  float acc[4][4] = {{0.0f, 0.0f, 0.0f, 0.0f},
                     {0.0f, 0.0f, 0.0f, 0.0f},
                     {0.0f, 0.0f, 0.0f, 0.0f},
                     {0.0f, 0.0f, 0.0f, 0.0f}};

  for (int k0 = 0; k0 < Kdim; k0 += TILE_K) {
    // Global loads first (overlap with previous compute finishing)
    float4 a0 = *(const float4*)(A + (size_t)(m0 + am) * lda + k0 + ak);
    float4 a1 = *(const float4*)(A + (size_t)(m0 + am + 32) * lda + k0 + ak);
    float4 b0, b1;
    if (B_NT) {
      b0 = *(const float4*)(Bm + (size_t)(n0 + am) * ldb + k0 + ak);
      b1 = *(const float4*)(Bm + (size_t)(n0 + am + 32) * ldb + k0 + ak);
    } else {
      b0 = *(const float4*)(Bm + (size_t)(k0 + bk_) * ldb + n0 + bn);
      b1 = *(const float4*)(Bm + (size_t)(k0 + bk_ + 16) * ldb + n0 + bn);
    }

    __syncthreads();  // previous iteration's compute must be done before overwrite

    // Transposed store: As[k][m]
    As[ak + 0][am] = a0.x; As[ak + 1][am] = a0.y;
    As[ak + 2][am] = a0.z; As[ak + 3][am] = a0.w;
    As[ak + 0][am + 32] = a1.x; As[ak + 1][am + 32] = a1.y;
    As[ak + 2][am + 32] = a1.z; As[ak + 3][am + 32] = a1.w;
    if (B_NT) {
      Bs[ak + 0][am] = b0.x; Bs[ak + 1][am] = b0.y;
      Bs[ak + 2][am] = b0.z; Bs[ak + 3][am] = b0.w;
      Bs[ak + 0][am + 32] = b1.x; Bs[ak + 1][am + 32] = b1.y;
      Bs[ak + 2][am + 32] = b1.z; Bs[ak + 3][am + 32] = b1.w;
    } else {
      *(float4*)&Bs[bk_][bn] = b0;
      *(float4*)&Bs[bk_ + 16][bn] = b1;
    }

    __syncthreads();

#pragma unroll
    for (int kk = 0; kk < TILE_K; ++kk) {
      float4 av = *(const float4*)&As[kk][ty << 2];
      float4 bv4 = *(const float4*)&Bs[kk][tx << 2];
      acc[0][0] += av.x * bv4.x; acc[0][1] += av.x * bv4.y;
      acc[0][2] += av.x * bv4.z; acc[0][3] += av.x * bv4.w;
      acc[1][0] += av.y * bv4.x; acc[1][1] += av.y * bv4.y;
      acc[1][2] += av.y * bv4.z; acc[1][3] += av.y * bv4.w;
      acc[2][0] += av.z * bv4.x; acc[2][1] += av.z * bv4.y;
      acc[2][2] += av.z * bv4.z; acc[2][3] += av.z * bv4.w;
      acc[3][0] += av.w * bv4.x; acc[3][1] += av.w * bv4.y;
      acc[3][2] += av.w * bv4.z; acc[3][3] += av.w * bv4.w;
    }
  }

  float4 badd = {0.0f, 0.0f, 0.0f, 0.0f};
  if (HAS_BIAS) badd = *(const float4*)(bias + n0 + (tx << 2));
#pragma unroll
  for (int r = 0; r < 4; ++r) {
    float4 o;
    o.x = acc[r][0] + badd.x;
    o.y = acc[r][1] + badd.y;
    o.z = acc[r][2] + badd.z;
    o.w = acc[r][3] + badd.w;
    *(float4*)(C + (size_t)(m0 + (ty << 2) + r) * ldc + n0 + (tx << 2)) = o;
  }
}

template <bool B_NT, bool HAS_BIAS>
__global__ __launch_bounds__(256, 4) void gemm_kernel(
    const float* __restrict__ A, const float* __restrict__ Bm,
    const float* __restrict__ bias, float* __restrict__ C,
    int lda, int ldb, int ldc, int Kdim) {
  gemm_body<B_NT, HAS_BIAS>(A, Bm, bias, C, lda, ldb, ldc, Kdim);
}

// Fused QKV projection: blockIdx.z selects {Wq,bq,Q}, {Wk,bk,K}, {Wv,bv,V}.
// q[n,e] = sum_d x[n,d] * W[e,d] + b[e]  -> NT GEMM with bias.
__global__ __launch_bounds__(256, 4) void qkv_kernel(
    const float* __restrict__ x,
    const float* __restrict__ Wq, const float* __restrict__ bq,
    const float* __restrict__ Wk, const float* __restrict__ bk,
    const float* __restrict__ Wv, const float* __restrict__ bv,
    float* __restrict__ Q, float* __restrict__ K, float* __restrict__ V) {
  const float* W;
  const float* bias;
  float* C;
  if (blockIdx.z == 0)      { W = Wq; bias = bq; C = Q; }
  else if (blockIdx.z == 1) { W = Wk; bias = bk; C = K; }
  else                      { W = Wv; bias = bv; C = V; }
  gemm_body<true, true>(x, W, bias, C, 512, 512, 512, 512);
}

// Row softmax over ncols=2048. One block (256 threads) per row; row lives in
// registers (8 floats/thread): one global read + one global write.
__global__ __launch_bounds__(256) void softmax_kernel(float* __restrict__ S,
                                                      int ncols) {
  __shared__ float red[8];
  float4* rowp = (float4*)(S + (size_t)blockIdx.x * ncols);
  const int tid = threadIdx.x;
  float4 v0 = rowp[tid];
  float4 v1 = rowp[tid + 256];

  float mx = fmaxf(fmaxf(fmaxf(v0.x, v0.y), fmaxf(v0.z, v0.w)),
                   fmaxf(fmaxf(v1.x, v1.y), fmaxf(v1.z, v1.w)));
#pragma unroll
  for (int off = 32; off >= 1; off >>= 1) mx = fmaxf(mx, __shfl_xor(mx, off));
  const int wid = tid >> 6;
  const int lane = tid & 63;
  if (lane == 0) red[wid] = mx;
  __syncthreads();
  if (tid == 0) red[4] = fmaxf(fmaxf(red[0], red[1]), fmaxf(red[2], red[3]));
  __syncthreads();
  mx = red[4];

  v0.x = __expf(v0.x - mx); v0.y = __expf(v0.y - mx);
  v0.z = __expf(v0.z - mx); v0.w = __expf(v0.w - mx);
  v1.x = __expf(v1.x - mx); v1.y = __expf(v1.y - mx);
  v1.z = __expf(v1.z - mx); v1.w = __expf(v1.w - mx);

  float s = v0.x + v0.y + v0.z + v0.w + v1.x + v1.y + v1.z + v1.w;
#pragma unroll
  for (int off = 32; off >= 1; off >>= 1) s += __shfl_xor(s, off);
  __syncthreads();  // guard red reuse
  if (lane == 0) red[wid] = s;
  __syncthreads();
  if (tid == 0) red[4] = red[0] + red[1] + red[2] + red[3];
  __syncthreads();
  const float inv = 1.0f / red[4];

  v0.x *= inv; v0.y *= inv; v0.z *= inv; v0.w *= inv;
  v1.x *= inv; v1.y *= inv; v1.z *= inv; v1.w *= inv;
  rowp[tid] = v0;
  rowp[tid + 256] = v1;
}

extern "C" void kernel_launch(void* const* d_in, const int* in_sizes, int n_in,
                              void* d_out, int out_size, void* d_ws,
                              size_t ws_size, hipStream_t stream) {
  (void)in_sizes; (void)n_in; (void)out_size; (void)ws_size;
  const int B = 8, N = 2048, D = 512;

  const float* x  = (const float*)d_in[0];
  const float* Wq = (const float*)d_in[1];
  const float* bq = (const float*)d_in[2];
  const float* Wk = (const float*)d_in[3];
  const float* bk = (const float*)d_in[4];
  const float* Wv = (const float*)d_in[5];
  const float* bv = (const float*)d_in[6];
  float* out = (float*)d_out;

  // Per-batch workspace layout (reused across batches): Q,K,V [N*D] + S [N*N]
  // Total: 3*4MB + 16.78MB = 29.4 MB.
  float* ws = (float*)d_ws;
  float* Q  = ws;
  float* Kp = ws + (size_t)N * D;
  float* V  = ws + (size_t)2 * N * D;
  float* S  = ws + (size_t)3 * N * D;

  for (int b = 0; b < B; ++b) {
    const float* xb = x + (size_t)b * N * D;
    float* outb = out + (size_t)b * N * D;

    // 1) QKV projection: M=N(2048) x N(512) x K(512), z = {q,k,v}
    qkv_kernel<<<dim3(D / TILE_N, N / TILE_M, 3), 256, 0, stream>>>(
        xb, Wq, bq, Wk, bk, Wv, bv, Q, Kp, V);

    // 2) S = Q * K^T : M=2048, N=2048, K=512 (NT)
    gemm_kernel<true, false><<<dim3(N / TILE_N, N / TILE_M), 256, 0, stream>>>(
        Q, Kp, nullptr, S, D, D, N, D);

    // 3) softmax rows of S
    softmax_kernel<<<N, 256, 0, stream>>>(S, N);

    // 4) out = P * V : M=2048, N=512, K=2048 (NN)
    gemm_kernel<false, false><<<dim3(D / TILE_N, N / TILE_M), 256, 0, stream>>>(
        S, V, nullptr, outb, N, D, D, N);
  }
}

// Round 2
// 520.206 us; speedup vs baseline: 3.4925x; 3.4925x over previous
//
#include <hip/hip_runtime.h>

typedef __attribute__((ext_vector_type(8))) short bf16x8;          // 8 bf16 (4 VGPRs)
typedef __attribute__((ext_vector_type(8))) unsigned short u16x8;  // 16B chunk
typedef __attribute__((ext_vector_type(4))) float f32x4;
typedef unsigned short u16;

__device__ __forceinline__ u16 f2bf(float f) {  // round-to-nearest-even bf16
  unsigned u = __float_as_uint(f);
  u += 0x7fffu + ((u >> 16) & 1u);
  return (u16)(u >> 16);
}
__device__ __forceinline__ float bf2f(u16 h) {
  return __uint_as_float((unsigned)h << 16);
}

// ---------------- fp32 -> bf16 hi/lo split (elementwise) ----------------
__global__ __launch_bounds__(256) void split_kernel(const float* __restrict__ in,
                                                    u16* __restrict__ hi,
                                                    u16* __restrict__ lo, int n8) {
  int t = blockIdx.x * 256 + threadIdx.x;
  if (t >= n8) return;
  const float4* p = (const float4*)in;
  float4 a = p[2 * t], b = p[2 * t + 1];
  float v[8] = {a.x, a.y, a.z, a.w, b.x, b.y, b.z, b.w};
  u16x8 h, l;
#pragma unroll
  for (int i = 0; i < 8; ++i) {
    u16 hh = f2bf(v[i]);
    h[i] = hh;
    l[i] = f2bf(v[i] - bf2f(hh));
  }
  *(u16x8*)(hi + (size_t)t * 8) = h;
  *(u16x8*)(lo + (size_t)t * 8) = l;
}

// ---------------- MFMA GEMM core ----------------
// C[m,n] = sum_k A[m,k]*B[n,k] (both operands natural row-major [free][k] bf16).
// BM=BN=128, BK=32, 256 threads (4 waves), 64x64 per wave via 4x4 mfma 16x16x32.
// LDS layout per tile: [kblk=4][free=128][8] with +8 u16 pad per kblk block
// (stride 1032) -> bank = 4*(quad+f) mod 32 => conflict-free frag reads.
// SPLIT=true: A,B given as hi/lo pairs; 3 MFMA passes (hh, hl, lh).
#define TSTR 1032
#define TILE_U 4128

template <bool SPLIT>
__device__ __forceinline__ void gemm_core(u16* s,
                                          const u16* __restrict__ Ah,
                                          const u16* __restrict__ Al,
                                          const u16* __restrict__ Bh,
                                          const u16* __restrict__ Bl,
                                          int lda, int ldb, int Kdim,
                                          int m0, int n0, f32x4 acc[4][4]) {
  const int tid = threadIdx.x;
  const int lane = tid & 63;
  const int wave = tid >> 6;
  const int wm = wave >> 1, wn = wave & 1;
  const int quad = lane >> 4, l15 = lane & 15;
  const int sf = tid >> 2, sc = tid & 3;  // staging: row sf(+64), k-chunk sc

  u16* sA = s;
  u16* sB = s + TILE_U;
  u16* sAl = s + 2 * TILE_U;
  u16* sBl = s + 3 * TILE_U;

  const size_t ar0 = (size_t)(m0 + sf) * lda;
  const size_t ar1 = (size_t)(m0 + sf + 64) * lda;
  const size_t br0 = (size_t)(n0 + sf) * ldb;
  const size_t br1 = (size_t)(n0 + sf + 64) * ldb;
  const int sw = sc * TSTR + sf * 8;
  const int aoff = quad * TSTR + (wm * 64 + l15) * 8;
  const int boff = quad * TSTR + (wn * 64 + l15) * 8;

  for (int k0 = 0; k0 < Kdim; k0 += 32) {
    const int gk = k0 + sc * 8;
    u16x8 vah0 = *(const u16x8*)(Ah + ar0 + gk);
    u16x8 vah1 = *(const u16x8*)(Ah + ar1 + gk);
    u16x8 vbh0 = *(const u16x8*)(Bh + br0 + gk);
    u16x8 vbh1 = *(const u16x8*)(Bh + br1 + gk);
    u16x8 val0, val1, vbl0, vbl1;
    if (SPLIT) {
      val0 = *(const u16x8*)(Al + ar0 + gk);
      val1 = *(const u16x8*)(Al + ar1 + gk);
      vbl0 = *(const u16x8*)(Bl + br0 + gk);
      vbl1 = *(const u16x8*)(Bl + br1 + gk);
    }
    __syncthreads();  // previous tile's compute done
    *(u16x8*)(sA + sw) = vah0;
    *(u16x8*)(sA + sw + 512) = vah1;
    *(u16x8*)(sB + sw) = vbh0;
    *(u16x8*)(sB + sw + 512) = vbh1;
    if (SPLIT) {
      *(u16x8*)(sAl + sw) = val0;
      *(u16x8*)(sAl + sw + 512) = val1;
      *(u16x8*)(sBl + sw) = vbl0;
      *(u16x8*)(sBl + sw + 512) = vbl1;
    }
    __syncthreads();

    bf16x8 fah[4], fbh[4];
#pragma unroll
    for (int i = 0; i < 4; ++i) fah[i] = *(const bf16x8*)(sA + aoff + i * 128);
#pragma unroll
    for (int j = 0; j < 4; ++j) fbh[j] = *(const bf16x8*)(sB + boff + j * 128);
#pragma unroll
    for (int i = 0; i < 4; ++i)
#pragma unroll
      for (int j = 0; j < 4; ++j)
        acc[i][j] = __builtin_amdgcn_mfma_f32_16x16x32_bf16(fah[i], fbh[j],
                                                            acc[i][j], 0, 0, 0);
    if (SPLIT) {
      bf16x8 fal[4], fbl[4];
#pragma unroll
      for (int i = 0; i < 4; ++i) fal[i] = *(const bf16x8*)(sAl + aoff + i * 128);
#pragma unroll
      for (int j = 0; j < 4; ++j) fbl[j] = *(const bf16x8*)(sBl + boff + j * 128);
#pragma unroll
      for (int i = 0; i < 4; ++i)
#pragma unroll
        for (int j = 0; j < 4; ++j) {
          acc[i][j] = __builtin_amdgcn_mfma_f32_16x16x32_bf16(fah[i], fbl[j],
                                                              acc[i][j], 0, 0, 0);
          acc[i][j] = __builtin_amdgcn_mfma_f32_16x16x32_bf16(fal[i], fbh[j],
                                                              acc[i][j], 0, 0, 0);
        }
    }
  }
}

// C/D layout (m89-verified): row m = quad*4 + reg, col n = lane&15.
#define EPI_IDX()                                       \
  const int lane = threadIdx.x & 63;                    \
  const int wave = threadIdx.x >> 6;                    \
  const int quad = lane >> 4, l15 = lane & 15;          \
  const int wm = wave >> 1, wn = wave & 1;              \
  const int em = (int)blockIdx.y * 128 + wm * 64 + quad * 4; \
  const int en = (int)blockIdx.x * 128 + wn * 64 + l15;

template <bool SPLIT>
__global__ __launch_bounds__(256, 2) void gemm_f32(
    const u16* __restrict__ Ah, const u16* __restrict__ Al,
    const u16* __restrict__ Bh, const u16* __restrict__ Bl,
    float* __restrict__ C, int lda, int ldb, int ldc, int Kdim,
    size_t aStride, size_t bStride, size_t cStride) {
  __shared__ u16 s[(SPLIT ? 4 : 2) * TILE_U];
  const int z = blockIdx.z;
  f32x4 acc[4][4];
  const f32x4 zero = {0.0f, 0.0f, 0.0f, 0.0f};
#pragma unroll
  for (int i = 0; i < 4; ++i)
#pragma unroll
    for (int j = 0; j < 4; ++j) acc[i][j] = zero;
  gemm_core<SPLIT>(s, Ah + z * aStride, SPLIT ? Al + z * aStride : Al,
                   Bh + z * bStride, SPLIT ? Bl + z * bStride : Bl, lda, ldb,
                   Kdim, blockIdx.y * 128, blockIdx.x * 128, acc);
  float* Cz = C + z * cStride;
  EPI_IDX();
#pragma unroll
  for (int i = 0; i < 4; ++i)
#pragma unroll
    for (int r = 0; r < 4; ++r) {
      size_t row = (size_t)(em + i * 16 + r) * ldc;
#pragma unroll
      for (int j = 0; j < 4; ++j) Cz[row + en + j * 16] = acc[i][j][r];
    }
}

// QKV: z=0 -> Q (hi/lo), z=1 -> K (hi/lo), z=2 -> V (single bf16, transposed Vt[e][m]).
__global__ __launch_bounds__(256, 2) void gemm_qkv(
    const u16* __restrict__ xh, const u16* __restrict__ xl,
    const u16* __restrict__ Wqh, const u16* __restrict__ Wql,
    const u16* __restrict__ Wkh, const u16* __restrict__ Wkl,
    const u16* __restrict__ Wvh, const u16* __restrict__ Wvl,
    const float* __restrict__ bq, const float* __restrict__ bk,
    const float* __restrict__ bv, u16* __restrict__ Qh, u16* __restrict__ Ql,
    u16* __restrict__ Kh, u16* __restrict__ Kl, u16* __restrict__ Vt,
    int ldvt) {
  __shared__ u16 s[4 * TILE_U];
  const int z = blockIdx.z;
  const u16 *Wh, *Wl;
  const float* bias;
  if (z == 0) { Wh = Wqh; Wl = Wql; bias = bq; }
  else if (z == 1) { Wh = Wkh; Wl = Wkl; bias = bk; }
  else { Wh = Wvh; Wl = Wvl; bias = bv; }
  f32x4 acc[4][4];
  const f32x4 zero = {0.0f, 0.0f, 0.0f, 0.0f};
#pragma unroll
  for (int i = 0; i < 4; ++i)
#pragma unroll
    for (int j = 0; j < 4; ++j) acc[i][j] = zero;
  gemm_core<true>(s, xh, xl, Wh, Wl, 512, 512, 512, blockIdx.y * 128,
                  blockIdx.x * 128, acc);
  EPI_IDX();
  float bj[4];
#pragma unroll
  for (int j = 0; j < 4; ++j) bj[j] = bias[en + j * 16];
  if (z < 2) {
    u16* Oh = (z == 0) ? Qh : Kh;
    u16* Ol = (z == 0) ? Ql : Kl;
#pragma unroll
    for (int i = 0; i < 4; ++i)
#pragma unroll
      for (int r = 0; r < 4; ++r) {
        size_t row = (size_t)(em + i * 16 + r) * 512;
#pragma unroll
        for (int j = 0; j < 4; ++j) {
          float v = acc[i][j][r] + bj[j];
          u16 h = f2bf(v);
          Oh[row + en + j * 16] = h;
          Ol[row + en + j * 16] = f2bf(v - bf2f(h));
        }
      }
  } else {
#pragma unroll
    for (int i = 0; i < 4; ++i)
#pragma unroll
      for (int r = 0; r < 4; ++r) {
        int m = em + i * 16 + r;
#pragma unroll
        for (int j = 0; j < 4; ++j) {
          float v = acc[i][j][r] + bj[j];
          Vt[(size_t)(en + j * 16) * ldvt + m] = f2bf(v);
        }
      }
  }
}

// ---------------- softmax (fp32 in -> bf16 out), row length 2048 ----------------
__global__ __launch_bounds__(256) void softmax_bf16(const float* __restrict__ S,
                                                    u16* __restrict__ P) {
  __shared__ float red[8];
  const int tid = threadIdx.x;
  const float4* src = (const float4*)(S + (size_t)blockIdx.x * 2048);
  float4 v0 = src[2 * tid], v1 = src[2 * tid + 1];

  float mx = fmaxf(fmaxf(fmaxf(v0.x, v0.y), fmaxf(v0.z, v0.w)),
                   fmaxf(fmaxf(v1.x, v1.y), fmaxf(v1.z, v1.w)));
#pragma unroll
  for (int off = 32; off >= 1; off >>= 1) mx = fmaxf(mx, __shfl_xor(mx, off));
  const int wid = tid >> 6, lane = tid & 63;
  if (lane == 0) red[wid] = mx;
  __syncthreads();
  if (tid == 0) red[4] = fmaxf(fmaxf(red[0], red[1]), fmaxf(red[2], red[3]));
  __syncthreads();
  mx = red[4];

  v0.x = __expf(v0.x - mx); v0.y = __expf(v0.y - mx);
  v0.z = __expf(v0.z - mx); v0.w = __expf(v0.w - mx);
  v1.x = __expf(v1.x - mx); v1.y = __expf(v1.y - mx);
  v1.z = __expf(v1.z - mx); v1.w = __expf(v1.w - mx);

  float sm = v0.x + v0.y + v0.z + v0.w + v1.x + v1.y + v1.z + v1.w;
#pragma unroll
  for (int off = 32; off >= 1; off >>= 1) sm += __shfl_xor(sm, off);
  __syncthreads();
  if (lane == 0) red[wid] = sm;
  __syncthreads();
  if (tid == 0) red[5] = red[0] + red[1] + red[2] + red[3];
  __syncthreads();
  const float inv = 1.0f / red[5];

  u16x8 o;
  o[0] = f2bf(v0.x * inv); o[1] = f2bf(v0.y * inv);
  o[2] = f2bf(v0.z * inv); o[3] = f2bf(v0.w * inv);
  o[4] = f2bf(v1.x * inv); o[5] = f2bf(v1.y * inv);
  o[6] = f2bf(v1.z * inv); o[7] = f2bf(v1.w * inv);
  *(u16x8*)(P + (size_t)blockIdx.x * 2048 + tid * 8) = o;
}

// ================= fp32 fallback (round-0, proven; used only if ws too small) ====
#define LTILE_M 64
#define LTILE_N 64
#define LTILE_K 32
template <bool B_NT, bool HAS_BIAS>
__device__ __forceinline__ void gemm_body_leg(const float* __restrict__ A,
                                              const float* __restrict__ Bm,
                                              const float* __restrict__ bias,
                                              float* __restrict__ C, int lda,
                                              int ldb, int ldc, int Kdim) {
  __shared__ float As[LTILE_K][LTILE_M + 4];
  __shared__ float Bs[LTILE_K][LTILE_N + 4];
  const int tid = threadIdx.x;
  const int tx = tid & 15, ty = tid >> 4;
  const int m0 = blockIdx.y * LTILE_M, n0 = blockIdx.x * LTILE_N;
  const int am = tid >> 3, ak = (tid & 7) << 2;
  const int bk_ = tid >> 4, bn = (tid & 15) << 2;
  float acc[4][4] = {};
  for (int k0 = 0; k0 < Kdim; k0 += LTILE_K) {
    float4 a0 = *(const float4*)(A + (size_t)(m0 + am) * lda + k0 + ak);
    float4 a1 = *(const float4*)(A + (size_t)(m0 + am + 32) * lda + k0 + ak);
    float4 b0, b1;
    if (B_NT) {
      b0 = *(const float4*)(Bm + (size_t)(n0 + am) * ldb + k0 + ak);
      b1 = *(const float4*)(Bm + (size_t)(n0 + am + 32) * ldb + k0 + ak);
    } else {
      b0 = *(const float4*)(Bm + (size_t)(k0 + bk_) * ldb + n0 + bn);
      b1 = *(const float4*)(Bm + (size_t)(k0 + bk_ + 16) * ldb + n0 + bn);
    }
    __syncthreads();
    As[ak + 0][am] = a0.x; As[ak + 1][am] = a0.y;
    As[ak + 2][am] = a0.z; As[ak + 3][am] = a0.w;
    As[ak + 0][am + 32] = a1.x; As[ak + 1][am + 32] = a1.y;
    As[ak + 2][am + 32] = a1.z; As[ak + 3][am + 32] = a1.w;
    if (B_NT) {
      Bs[ak + 0][am] = b0.x; Bs[ak + 1][am] = b0.y;
      Bs[ak + 2][am] = b0.z; Bs[ak + 3][am] = b0.w;
      Bs[ak + 0][am + 32] = b1.x; Bs[ak + 1][am + 32] = b1.y;
      Bs[ak + 2][am + 32] = b1.z; Bs[ak + 3][am + 32] = b1.w;
    } else {
      *(float4*)&Bs[bk_][bn] = b0;
      *(float4*)&Bs[bk_ + 16][bn] = b1;
    }
    __syncthreads();
#pragma unroll
    for (int kk = 0; kk < LTILE_K; ++kk) {
      float4 av = *(const float4*)&As[kk][ty << 2];
      float4 bv4 = *(const float4*)&Bs[kk][tx << 2];
      acc[0][0] += av.x * bv4.x; acc[0][1] += av.x * bv4.y;
      acc[0][2] += av.x * bv4.z; acc[0][3] += av.x * bv4.w;
      acc[1][0] += av.y * bv4.x; acc[1][1] += av.y * bv4.y;
      acc[1][2] += av.y * bv4.z; acc[1][3] += av.y * bv4.w;
      acc[2][0] += av.z * bv4.x; acc[2][1] += av.z * bv4.y;
      acc[2][2] += av.z * bv4.z; acc[2][3] += av.z * bv4.w;
      acc[3][0] += av.w * bv4.x; acc[3][1] += av.w * bv4.y;
      acc[3][2] += av.w * bv4.z; acc[3][3] += av.w * bv4.w;
    }
  }
  float4 badd = {0.0f, 0.0f, 0.0f, 0.0f};
  if (HAS_BIAS) badd = *(const float4*)(bias + n0 + (tx << 2));
#pragma unroll
  for (int r = 0; r < 4; ++r) {
    float4 o;
    o.x = acc[r][0] + badd.x; o.y = acc[r][1] + badd.y;
    o.z = acc[r][2] + badd.z; o.w = acc[r][3] + badd.w;
    *(float4*)(C + (size_t)(m0 + (ty << 2) + r) * ldc + n0 + (tx << 2)) = o;
  }
}
template <bool B_NT, bool HAS_BIAS>
__global__ __launch_bounds__(256, 4) void gemm_leg(const float* A, const float* Bm,
                                                   const float* bias, float* C,
                                                   int lda, int ldb, int ldc,
                                                   int Kdim) {
  gemm_body_leg<B_NT, HAS_BIAS>(A, Bm, bias, C, lda, ldb, ldc, Kdim);
}
__global__ __launch_bounds__(256, 4) void qkv_leg(
    const float* x, const float* Wq, const float* bq, const float* Wk,
    const float* bk, const float* Wv, const float* bv, float* Q, float* K,
    float* V) {
  const float *W, *bias;
  float* C;
  if (blockIdx.z == 0) { W = Wq; bias = bq; C = Q; }
  else if (blockIdx.z == 1) { W = Wk; bias = bk; C = K; }
  else { W = Wv; bias = bv; C = V; }
  gemm_body_leg<true, true>(x, W, bias, C, 512, 512, 512, 512);
}
__global__ __launch_bounds__(256) void softmax_leg(float* S, int ncols) {
  __shared__ float red[8];
  float4* rowp = (float4*)(S + (size_t)blockIdx.x * ncols);
  const int tid = threadIdx.x;
  float4 v0 = rowp[tid], v1 = rowp[tid + 256];
  float mx = fmaxf(fmaxf(fmaxf(v0.x, v0.y), fmaxf(v0.z, v0.w)),
                   fmaxf(fmaxf(v1.x, v1.y), fmaxf(v1.z, v1.w)));
#pragma unroll
  for (int off = 32; off >= 1; off >>= 1) mx = fmaxf(mx, __shfl_xor(mx, off));
  const int wid = tid >> 6, lane = tid & 63;
  if (lane == 0) red[wid] = mx;
  __syncthreads();
  if (tid == 0) red[4] = fmaxf(fmaxf(red[0], red[1]), fmaxf(red[2], red[3]));
  __syncthreads();
  mx = red[4];
  v0.x = __expf(v0.x - mx); v0.y = __expf(v0.y - mx);
  v0.z = __expf(v0.z - mx); v0.w = __expf(v0.w - mx);
  v1.x = __expf(v1.x - mx); v1.y = __expf(v1.y - mx);
  v1.z = __expf(v1.z - mx); v1.w = __expf(v1.w - mx);
  float sm = v0.x + v0.y + v0.z + v0.w + v1.x + v1.y + v1.z + v1.w;
#pragma unroll
  for (int off = 32; off >= 1; off >>= 1) sm += __shfl_xor(sm, off);
  __syncthreads();
  if (lane == 0) red[wid] = sm;
  __syncthreads();
  if (tid == 0) red[5] = red[0] + red[1] + red[2] + red[3];
  __syncthreads();
  const float inv = 1.0f / red[5];
  v0.x *= inv; v0.y *= inv; v0.z *= inv; v0.w *= inv;
  v1.x *= inv; v1.y *= inv; v1.z *= inv; v1.w *= inv;
  rowp[tid] = v0;
  rowp[tid + 256] = v1;
}

// ================================ host ================================
extern "C" void kernel_launch(void* const* d_in, const int* in_sizes, int n_in,
                              void* d_out, int out_size, void* d_ws,
                              size_t ws_size, hipStream_t stream) {
  (void)in_sizes; (void)n_in; (void)out_size;
  const int B = 8, N = 2048, D = 512;
  const size_t ND = (size_t)N * D;    // 1,048,576
  const size_t NN = (size_t)N * N;    // 4,194,304
  const float* x = (const float*)d_in[0];
  const float* Wf[3] = {(const float*)d_in[1], (const float*)d_in[3],
                        (const float*)d_in[5]};
  const float* bq = (const float*)d_in[2];
  const float* bk = (const float*)d_in[4];
  const float* bv = (const float*)d_in[6];
  float* out = (float*)d_out;

  char* w = (char*)d_ws;
  auto take = [&](size_t bytes) {
    char* p = w;
    w += (bytes + 255) & ~(size_t)255;
    return p;
  };

  if (ws_size >= 326000000ULL) {
    // ---- Path A: fully batched ----
    u16 *Wh[3], *Wl[3];
    for (int i = 0; i < 3; ++i) {
      Wh[i] = (u16*)take(524288);
      Wl[i] = (u16*)take(524288);
    }
    u16* xh = (u16*)take(2 * B * ND);  u16* xl = (u16*)take(2 * B * ND);
    u16* Qh = (u16*)take(2 * B * ND);  u16* Ql = (u16*)take(2 * B * ND);
    u16* Kh = (u16*)take(2 * B * ND);  u16* Kl = (u16*)take(2 * B * ND);
    u16* Vt = (u16*)take(2 * B * ND);
    float* S = (float*)take(4 * B * NN);
    u16* P = (u16*)take(2 * B * NN);

    split_kernel<<<4096, 256, 0, stream>>>(x, xh, xl, (int)(B * ND / 8));
    for (int i = 0; i < 3; ++i)
      split_kernel<<<128, 256, 0, stream>>>(Wf[i], Wh[i], Wl[i], 32768);
    gemm_qkv<<<dim3(4, 128, 3), 256, 0, stream>>>(
        xh, xl, Wh[0], Wl[0], Wh[1], Wl[1], Wh[2], Wl[2], bq, bk, bv, Qh, Ql,
        Kh, Kl, Vt, B * N);
    gemm_f32<true><<<dim3(16, 16, 8), 256, 0, stream>>>(
        Qh, Ql, Kh, Kl, S, 512, 512, 2048, 512, ND, ND, NN);
    softmax_bf16<<<B * N, 256, 0, stream>>>(S, P);
    gemm_f32<false><<<dim3(4, 16, 8), 256, 0, stream>>>(
        P, nullptr, Vt, nullptr, out, 2048, B * N, 512, 2048, NN, (size_t)N, ND);
  } else if (ws_size >= 208000000ULL) {
    // ---- Path B: batched QKV/PV, per-batch scores+softmax (single S buffer) ----
    u16 *Wh[3], *Wl[3];
    for (int i = 0; i < 3; ++i) {
      Wh[i] = (u16*)take(524288);
      Wl[i] = (u16*)take(524288);
    }
    u16* xh = (u16*)take(2 * B * ND);  u16* xl = (u16*)take(2 * B * ND);
    u16* Qh = (u16*)take(2 * B * ND);  u16* Ql = (u16*)take(2 * B * ND);
    u16* Kh = (u16*)take(2 * B * ND);  u16* Kl = (u16*)take(2 * B * ND);
    u16* Vt = (u16*)take(2 * B * ND);
    float* S = (float*)take(4 * NN);
    u16* P = (u16*)take(2 * B * NN);

    split_kernel<<<4096, 256, 0, stream>>>(x, xh, xl, (int)(B * ND / 8));
    for (int i = 0; i < 3; ++i)
      split_kernel<<<128, 256, 0, stream>>>(Wf[i], Wh[i], Wl[i], 32768);
    gemm_qkv<<<dim3(4, 128, 3), 256, 0, stream>>>(
        xh, xl, Wh[0], Wl[0], Wh[1], Wl[1], Wh[2], Wl[2], bq, bk, bv, Qh, Ql,
        Kh, Kl, Vt, B * N);
    for (int b = 0; b < B; ++b) {
      gemm_f32<true><<<dim3(16, 16, 1), 256, 0, stream>>>(
          Qh + b * ND, Ql + b * ND, Kh + b * ND, Kl + b * ND, S, 512, 512, 2048,
          512, 0, 0, 0);
      softmax_bf16<<<N, 256, 0, stream>>>(S, P + b * NN);
    }
    gemm_f32<false><<<dim3(4, 16, 8), 256, 0, stream>>>(
        P, nullptr, Vt, nullptr, out, 2048, B * N, 512, 2048, NN, (size_t)N, ND);
  } else if (ws_size >= 44500000ULL) {
    // ---- Path C: per-batch everything ----
    u16 *Wh[3], *Wl[3];
    for (int i = 0; i < 3; ++i) {
      Wh[i] = (u16*)take(524288);
      Wl[i] = (u16*)take(524288);
    }
    u16* xh = (u16*)take(2 * ND);  u16* xl = (u16*)take(2 * ND);
    u16* Qh = (u16*)take(2 * ND);  u16* Ql = (u16*)take(2 * ND);
    u16* Kh = (u16*)take(2 * ND);  u16* Kl = (u16*)take(2 * ND);
    u16* Vt = (u16*)take(2 * ND);
    float* S = (float*)take(4 * NN);
    u16* P = (u16*)take(2 * NN);

    for (int i = 0; i < 3; ++i)
      split_kernel<<<128, 256, 0, stream>>>(Wf[i], Wh[i], Wl[i], 32768);
    for (int b = 0; b < B; ++b) {
      split_kernel<<<512, 256, 0, stream>>>(x + b * ND, xh, xl, (int)(ND / 8));
      gemm_qkv<<<dim3(4, 16, 3), 256, 0, stream>>>(
          xh, xl, Wh[0], Wl[0], Wh[1], Wl[1], Wh[2], Wl[2], bq, bk, bv, Qh, Ql,
          Kh, Kl, Vt, N);
      gemm_f32<true><<<dim3(16, 16, 1), 256, 0, stream>>>(
          Qh, Ql, Kh, Kl, S, 512, 512, 2048, 512, 0, 0, 0);
      softmax_bf16<<<N, 256, 0, stream>>>(S, P);
      gemm_f32<false><<<dim3(4, 16, 1), 256, 0, stream>>>(
          P, nullptr, Vt, nullptr, out + b * ND, 2048, 2048, 512, 2048, 0, 0, 0);
    }
  } else {
    // ---- fp32 fallback (round-0 path, 29.4 MB) ----
    float* ws = (float*)d_ws;
    float* Q = ws;
    float* Kp = ws + ND;
    float* V = ws + 2 * ND;
    float* S = ws + 3 * ND;
    for (int b = 0; b < B; ++b) {
      const float* xb = x + b * ND;
      float* outb = out + b * ND;
      qkv_leg<<<dim3(8, 32, 3), 256, 0, stream>>>(xb, Wf[0], bq, Wf[1], bk,
                                                  Wf[2], bv, Q, Kp, V);
      gemm_leg<true, false><<<dim3(32, 32), 256, 0, stream>>>(Q, Kp, nullptr, S,
                                                              512, 512, 2048, 512);
      softmax_leg<<<N, 256, 0, stream>>>(S, N);
      gemm_leg<false, false><<<dim3(8, 32), 256, 0, stream>>>(S, V, nullptr,
                                                              outb, 2048, 512,
                                                              512, 2048);
    }
  }
}

// Round 3
// 482.184 us; speedup vs baseline: 3.7679x; 1.0789x over previous
//
#include <hip/hip_runtime.h>

typedef __attribute__((ext_vector_type(8))) short bf16x8;          // 8 bf16 (4 VGPRs)
typedef __attribute__((ext_vector_type(8))) unsigned short u16x8;  // 16B chunk
typedef __attribute__((ext_vector_type(4))) float f32x4;
typedef unsigned short u16;

__device__ __forceinline__ u16 f2bf(float f) {  // round-to-nearest-even bf16
  unsigned u = __float_as_uint(f);
  u += 0x7fffu + ((u >> 16) & 1u);
  return (u16)(u >> 16);
}
__device__ __forceinline__ float bf2f(u16 h) {
  return __uint_as_float((unsigned)h << 16);
}

// Async global->LDS DMA, 16B per lane. LDS dest semantics: wave-uniform base +
// lane*16 (m104) — our per-lane pointers are exactly base + lane*16B.
__device__ __forceinline__ void gl_lds16(const u16* g, u16* l) {
  __builtin_amdgcn_global_load_lds(
      (const __attribute__((address_space(1))) void*)g,
      (__attribute__((address_space(3))) void*)l, 16, 0, 0);
}

// ---------------- fp32 -> bf16 hi/lo split (elementwise) ----------------
__global__ __launch_bounds__(256) void split_kernel(const float* __restrict__ in,
                                                    u16* __restrict__ hi,
                                                    u16* __restrict__ lo, int n8) {
  int t = blockIdx.x * 256 + threadIdx.x;
  if (t >= n8) return;
  const float4* p = (const float4*)in;
  float4 a = p[2 * t], b = p[2 * t + 1];
  float v[8] = {a.x, a.y, a.z, a.w, b.x, b.y, b.z, b.w};
  u16x8 h, l;
#pragma unroll
  for (int i = 0; i < 8; ++i) {
    u16 hh = f2bf(v[i]);
    h[i] = hh;
    l[i] = f2bf(v[i] - bf2f(hh));
  }
  *(u16x8*)(hi + (size_t)t * 8) = h;
  *(u16x8*)(lo + (size_t)t * 8) = l;
}

// ---------------- MFMA GEMM core (global_load_lds staging) ----------------
// C[m,n] = sum_k A[m,k]*B[n,k], both operands row-major [free][k] bf16.
// BM=BN=128, BK=32, 256 threads (4 waves), 64x64 per wave via 4x4 mfma
// 16x16x32. LDS per matrix: [row 0..127][32 u16] unpadded (8 KB), staged by
// 2 global_load_lds-dwordx4 per wave per matrix per k-step. Frag reads
// ds_read_b128 spread evenly over all 32 banks.
// PASSES=3: A,B as hi/lo pairs; hh + hl + lh MFMA passes (~fp32 accuracy).
template <int PASSES>
__device__ __forceinline__ void mfma_core(u16* s, const u16* __restrict__ Ah,
                                          const u16* __restrict__ Al,
                                          const u16* __restrict__ Bh,
                                          const u16* __restrict__ Bl,
                                          int lda, int ldb, int Kdim,
                                          int m0, int n0, f32x4 acc[4][4]) {
  const int tid = threadIdx.x;
  const int l = tid & 63, w = tid >> 6;
  const int wm = w >> 1, wn = w & 1;
  const int quad = l >> 4, l15 = l & 15;
  const int srow = w * 32 + (l >> 2);  // staging row (and +16)
  const int skc = (l & 3) * 8;         // staging k offset (u16)

  u16* sA = s;
  u16* sB = s + 4096;
  u16* sAl = s + 8192;
  u16* sBl = s + 12288;

  const u16* gA0 = Ah + (size_t)(m0 + srow) * lda + skc;
  const u16* gB0 = Bh + (size_t)(n0 + srow) * ldb + skc;
  const u16* gAl0 = nullptr;
  const u16* gBl0 = nullptr;
  if (PASSES == 3) {
    gAl0 = Al + (size_t)(m0 + srow) * lda + skc;
    gBl0 = Bl + (size_t)(n0 + srow) * ldb + skc;
  }
  u16* lA0 = sA + srow * 32 + skc;  // == sA + w*1024 + lane*8 (16B/lane)
  u16* lB0 = sB + srow * 32 + skc;
  u16* lAl0 = sAl + srow * 32 + skc;
  u16* lBl0 = sBl + srow * 32 + skc;
  const size_t a16 = (size_t)16 * lda, b16 = (size_t)16 * ldb;

  const int afrag = (wm * 64 + l15) * 32 + quad * 8;  // u16 idx; +i*512 rows
  const int bfrag = (wn * 64 + l15) * 32 + quad * 8;

  for (int k0 = 0; k0 < Kdim; k0 += 32) {
    __syncthreads();  // previous tile's ds_reads done before DMA overwrite
    gl_lds16(gA0 + k0, lA0);
    gl_lds16(gA0 + k0 + a16, lA0 + 512);
    gl_lds16(gB0 + k0, lB0);
    gl_lds16(gB0 + k0 + b16, lB0 + 512);
    if (PASSES == 3) {
      gl_lds16(gAl0 + k0, lAl0);
      gl_lds16(gAl0 + k0 + a16, lAl0 + 512);
      gl_lds16(gBl0 + k0, lBl0);
      gl_lds16(gBl0 + k0 + b16, lBl0 + 512);
    }
    __syncthreads();  // drains vmcnt (DMA visible)

    bf16x8 fah[4], fbh[4];
#pragma unroll
    for (int i = 0; i < 4; ++i) fah[i] = *(const bf16x8*)(sA + afrag + i * 512);
#pragma unroll
    for (int j = 0; j < 4; ++j) fbh[j] = *(const bf16x8*)(sB + bfrag + j * 512);
#pragma unroll
    for (int i = 0; i < 4; ++i)
#pragma unroll
      for (int j = 0; j < 4; ++j)
        acc[i][j] = __builtin_amdgcn_mfma_f32_16x16x32_bf16(fah[i], fbh[j],
                                                            acc[i][j], 0, 0, 0);
    if (PASSES == 3) {
      bf16x8 fal[4], fbl[4];
#pragma unroll
      for (int i = 0; i < 4; ++i)
        fal[i] = *(const bf16x8*)(sAl + afrag + i * 512);
#pragma unroll
      for (int j = 0; j < 4; ++j)
        fbl[j] = *(const bf16x8*)(sBl + bfrag + j * 512);
#pragma unroll
      for (int i = 0; i < 4; ++i)
#pragma unroll
        for (int j = 0; j < 4; ++j) {
          acc[i][j] = __builtin_amdgcn_mfma_f32_16x16x32_bf16(fah[i], fbl[j],
                                                              acc[i][j], 0, 0, 0);
          acc[i][j] = __builtin_amdgcn_mfma_f32_16x16x32_bf16(fal[i], fbh[j],
                                                              acc[i][j], 0, 0, 0);
        }
    }
  }
}

// C/D layout (m89-verified): row m = quad*4 + reg, col n = lane&15.
template <int PASSES>
__global__ __launch_bounds__(256, 2) void gemm_f32k(
    const u16* __restrict__ Ah, const u16* __restrict__ Al,
    const u16* __restrict__ Bh, const u16* __restrict__ Bl,
    float* __restrict__ C, int lda, int ldb, int ldc, int Kdim,
    size_t aStride, size_t bStride, size_t cStride) {
  __shared__ u16 s[PASSES == 3 ? 16384 : 8192];
  const int z = blockIdx.z;
  f32x4 acc[4][4];
  const f32x4 zero = {0.0f, 0.0f, 0.0f, 0.0f};
#pragma unroll
  for (int i = 0; i < 4; ++i)
#pragma unroll
    for (int j = 0; j < 4; ++j) acc[i][j] = zero;
  mfma_core<PASSES>(s, Ah + z * aStride, (PASSES == 3) ? Al + z * aStride : Al,
                    Bh + z * bStride, (PASSES == 3) ? Bl + z * bStride : Bl,
                    lda, ldb, Kdim, blockIdx.y * 128, blockIdx.x * 128, acc);
  float* Cz = C + z * cStride;
  const int lane = threadIdx.x & 63;
  const int wave = threadIdx.x >> 6;
  const int quad = lane >> 4, l15 = lane & 15;
  const int em = (int)blockIdx.y * 128 + (wave >> 1) * 64 + quad * 4;
  const int en = (int)blockIdx.x * 128 + (wave & 1) * 64 + l15;
#pragma unroll
  for (int i = 0; i < 4; ++i)
#pragma unroll
    for (int r = 0; r < 4; ++r) {
      size_t row = (size_t)(em + i * 16 + r) * ldc;
#pragma unroll
      for (int j = 0; j < 4; ++j) Cz[row + en + j * 16] = acc[i][j][r];
    }
}

// QKV: blockIdx.x = (z<<2)|ntile so the 12 blocks sharing the same x-rows are
// consecutive (L3 temporal reuse of x). z=0 Q (hi/lo out, 3-pass), z=1 K
// (hi/lo out, 3-pass), z=2 V (1-pass, transposed bf16 out Vt[e][m]).
__global__ __launch_bounds__(256, 2) void gemm_qkv2(
    const u16* __restrict__ xh, const u16* __restrict__ xl,
    const u16* __restrict__ Wqh, const u16* __restrict__ Wql,
    const u16* __restrict__ Wkh, const u16* __restrict__ Wkl,
    const u16* __restrict__ Wvh, const float* __restrict__ bq,
    const float* __restrict__ bk, const float* __restrict__ bv,
    u16* __restrict__ Qh, u16* __restrict__ Ql, u16* __restrict__ Kh,
    u16* __restrict__ Kl, u16* __restrict__ Vt, int ldvt) {
  __shared__ u16 s[16384];
  const int z = blockIdx.x >> 2;
  const int n0 = (blockIdx.x & 3) * 128;
  const int m0 = blockIdx.y * 128;
  f32x4 acc[4][4];
  const f32x4 zero = {0.0f, 0.0f, 0.0f, 0.0f};
#pragma unroll
  for (int i = 0; i < 4; ++i)
#pragma unroll
    for (int j = 0; j < 4; ++j) acc[i][j] = zero;

  if (z == 2) {
    mfma_core<1>(s, xh, nullptr, Wvh, nullptr, 512, 512, 512, m0, n0, acc);
  } else if (z == 1) {
    mfma_core<3>(s, xh, xl, Wkh, Wkl, 512, 512, 512, m0, n0, acc);
  } else {
    mfma_core<3>(s, xh, xl, Wqh, Wql, 512, 512, 512, m0, n0, acc);
  }

  const float* bias = (z == 0) ? bq : (z == 1) ? bk : bv;
  const int lane = threadIdx.x & 63;
  const int wave = threadIdx.x >> 6;
  const int quad = lane >> 4, l15 = lane & 15;
  const int em = m0 + (wave >> 1) * 64 + quad * 4;
  const int en = n0 + (wave & 1) * 64 + l15;
  float bj[4];
#pragma unroll
  for (int j = 0; j < 4; ++j) bj[j] = bias[en + j * 16];
  if (z < 2) {
    u16* Oh = (z == 0) ? Qh : Kh;
    u16* Ol = (z == 0) ? Ql : Kl;
#pragma unroll
    for (int i = 0; i < 4; ++i)
#pragma unroll
      for (int r = 0; r < 4; ++r) {
        size_t row = (size_t)(em + i * 16 + r) * 512;
#pragma unroll
        for (int j = 0; j < 4; ++j) {
          float v = acc[i][j][r] + bj[j];
          u16 h = f2bf(v);
          Oh[row + en + j * 16] = h;
          Ol[row + en + j * 16] = f2bf(v - bf2f(h));
        }
      }
  } else {
#pragma unroll
    for (int i = 0; i < 4; ++i)
#pragma unroll
      for (int r = 0; r < 4; ++r) {
        int m = em + i * 16 + r;
#pragma unroll
        for (int j = 0; j < 4; ++j) {
          float v = acc[i][j][r] + bj[j];
          Vt[(size_t)(en + j * 16) * ldvt + m] = f2bf(v);
        }
      }
  }
}

// ---------------- softmax (fp32 in -> bf16 out), row length 2048 ----------------
__global__ __launch_bounds__(256) void softmax_bf16(const float* __restrict__ S,
                                                    u16* __restrict__ P) {
  __shared__ float red[8];
  const int tid = threadIdx.x;
  const float4* src = (const float4*)(S + (size_t)blockIdx.x * 2048);
  float4 v0 = src[2 * tid], v1 = src[2 * tid + 1];

  float mx = fmaxf(fmaxf(fmaxf(v0.x, v0.y), fmaxf(v0.z, v0.w)),
                   fmaxf(fmaxf(v1.x, v1.y), fmaxf(v1.z, v1.w)));
#pragma unroll
  for (int off = 32; off >= 1; off >>= 1) mx = fmaxf(mx, __shfl_xor(mx, off));
  const int wid = tid >> 6, lane = tid & 63;
  if (lane == 0) red[wid] = mx;
  __syncthreads();
  if (tid == 0) red[4] = fmaxf(fmaxf(red[0], red[1]), fmaxf(red[2], red[3]));
  __syncthreads();
  mx = red[4];

  v0.x = __expf(v0.x - mx); v0.y = __expf(v0.y - mx);
  v0.z = __expf(v0.z - mx); v0.w = __expf(v0.w - mx);
  v1.x = __expf(v1.x - mx); v1.y = __expf(v1.y - mx);
  v1.z = __expf(v1.z - mx); v1.w = __expf(v1.w - mx);

  float sm = v0.x + v0.y + v0.z + v0.w + v1.x + v1.y + v1.z + v1.w;
#pragma unroll
  for (int off = 32; off >= 1; off >>= 1) sm += __shfl_xor(sm, off);
  __syncthreads();
  if (lane == 0) red[wid] = sm;
  __syncthreads();
  if (tid == 0) red[5] = red[0] + red[1] + red[2] + red[3];
  __syncthreads();
  const float inv = 1.0f / red[5];

  u16x8 o;
  o[0] = f2bf(v0.x * inv); o[1] = f2bf(v0.y * inv);
  o[2] = f2bf(v0.z * inv); o[3] = f2bf(v0.w * inv);
  o[4] = f2bf(v1.x * inv); o[5] = f2bf(v1.y * inv);
  o[6] = f2bf(v1.z * inv); o[7] = f2bf(v1.w * inv);
  *(u16x8*)(P + (size_t)blockIdx.x * 2048 + tid * 8) = o;
}

// ================= fp32 fallback (round-0, proven; used only if ws tiny) ====
#define LTILE_M 64
#define LTILE_N 64
#define LTILE_K 32
template <bool B_NT, bool HAS_BIAS>
__device__ __forceinline__ void gemm_body_leg(const float* __restrict__ A,
                                              const float* __restrict__ Bm,
                                              const float* __restrict__ bias,
                                              float* __restrict__ C, int lda,
                                              int ldb, int ldc, int Kdim) {
  __shared__ float As[LTILE_K][LTILE_M + 4];
  __shared__ float Bs[LTILE_K][LTILE_N + 4];
  const int tid = threadIdx.x;
  const int tx = tid & 15, ty = tid >> 4;
  const int m0 = blockIdx.y * LTILE_M, n0 = blockIdx.x * LTILE_N;
  const int am = tid >> 3, ak = (tid & 7) << 2;
  const int bk_ = tid >> 4, bn = (tid & 15) << 2;
  float acc[4][4] = {};
  for (int k0 = 0; k0 < Kdim; k0 += LTILE_K) {
    float4 a0 = *(const float4*)(A + (size_t)(m0 + am) * lda + k0 + ak);
    float4 a1 = *(const float4*)(A + (size_t)(m0 + am + 32) * lda + k0 + ak);
    float4 b0, b1;
    if (B_NT) {
      b0 = *(const float4*)(Bm + (size_t)(n0 + am) * ldb + k0 + ak);
      b1 = *(const float4*)(Bm + (size_t)(n0 + am + 32) * ldb + k0 + ak);
    } else {
      b0 = *(const float4*)(Bm + (size_t)(k0 + bk_) * ldb + n0 + bn);
      b1 = *(const float4*)(Bm + (size_t)(k0 + bk_ + 16) * ldb + n0 + bn);
    }
    __syncthreads();
    As[ak + 0][am] = a0.x; As[ak + 1][am] = a0.y;
    As[ak + 2][am] = a0.z; As[ak + 3][am] = a0.w;
    As[ak + 0][am + 32] = a1.x; As[ak + 1][am + 32] = a1.y;
    As[ak + 2][am + 32] = a1.z; As[ak + 3][am + 32] = a1.w;
    if (B_NT) {
      Bs[ak + 0][am] = b0.x; Bs[ak + 1][am] = b0.y;
      Bs[ak + 2][am] = b0.z; Bs[ak + 3][am] = b0.w;
      Bs[ak + 0][am + 32] = b1.x; Bs[ak + 1][am + 32] = b1.y;
      Bs[ak + 2][am + 32] = b1.z; Bs[ak + 3][am + 32] = b1.w;
    } else {
      *(float4*)&Bs[bk_][bn] = b0;
      *(float4*)&Bs[bk_ + 16][bn] = b1;
    }
    __syncthreads();
#pragma unroll
    for (int kk = 0; kk < LTILE_K; ++kk) {
      float4 av = *(const float4*)&As[kk][ty << 2];
      float4 bv4 = *(const float4*)&Bs[kk][tx << 2];
      acc[0][0] += av.x * bv4.x; acc[0][1] += av.x * bv4.y;
      acc[0][2] += av.x * bv4.z; acc[0][3] += av.x * bv4.w;
      acc[1][0] += av.y * bv4.x; acc[1][1] += av.y * bv4.y;
      acc[1][2] += av.y * bv4.z; acc[1][3] += av.y * bv4.w;
      acc[2][0] += av.z * bv4.x; acc[2][1] += av.z * bv4.y;
      acc[2][2] += av.z * bv4.z; acc[2][3] += av.z * bv4.w;
      acc[3][0] += av.w * bv4.x; acc[3][1] += av.w * bv4.y;
      acc[3][2] += av.w * bv4.z; acc[3][3] += av.w * bv4.w;
    }
  }
  float4 badd = {0.0f, 0.0f, 0.0f, 0.0f};
  if (HAS_BIAS) badd = *(const float4*)(bias + n0 + (tx << 2));
#pragma unroll
  for (int r = 0; r < 4; ++r) {
    float4 o;
    o.x = acc[r][0] + badd.x; o.y = acc[r][1] + badd.y;
    o.z = acc[r][2] + badd.z; o.w = acc[r][3] + badd.w;
    *(float4*)(C + (size_t)(m0 + (ty << 2) + r) * ldc + n0 + (tx << 2)) = o;
  }
}
template <bool B_NT, bool HAS_BIAS>
__global__ __launch_bounds__(256, 4) void gemm_leg(const float* A, const float* Bm,
                                                   const float* bias, float* C,
                                                   int lda, int ldb, int ldc,
                                                   int Kdim) {
  gemm_body_leg<B_NT, HAS_BIAS>(A, Bm, bias, C, lda, ldb, ldc, Kdim);
}
__global__ __launch_bounds__(256, 4) void qkv_leg(
    const float* x, const float* Wq, const float* bq, const float* Wk,
    const float* bk, const float* Wv, const float* bv, float* Q, float* K,
    float* V) {
  const float *W, *bias;
  float* C;
  if (blockIdx.z == 0) { W = Wq; bias = bq; C = Q; }
  else if (blockIdx.z == 1) { W = Wk; bias = bk; C = K; }
  else { W = Wv; bias = bv; C = V; }
  gemm_body_leg<true, true>(x, W, bias, C, 512, 512, 512, 512);
}
__global__ __launch_bounds__(256) void softmax_leg(float* S, int ncols) {
  __shared__ float red[8];
  float4* rowp = (float4*)(S + (size_t)blockIdx.x * ncols);
  const int tid = threadIdx.x;
  float4 v0 = rowp[tid], v1 = rowp[tid + 256];
  float mx = fmaxf(fmaxf(fmaxf(v0.x, v0.y), fmaxf(v0.z, v0.w)),
                   fmaxf(fmaxf(v1.x, v1.y), fmaxf(v1.z, v1.w)));
#pragma unroll
  for (int off = 32; off >= 1; off >>= 1) mx = fmaxf(mx, __shfl_xor(mx, off));
  const int wid = tid >> 6, lane = tid & 63;
  if (lane == 0) red[wid] = mx;
  __syncthreads();
  if (tid == 0) red[4] = fmaxf(fmaxf(red[0], red[1]), fmaxf(red[2], red[3]));
  __syncthreads();
  mx = red[4];
  v0.x = __expf(v0.x - mx); v0.y = __expf(v0.y - mx);
  v0.z = __expf(v0.z - mx); v0.w = __expf(v0.w - mx);
  v1.x = __expf(v1.x - mx); v1.y = __expf(v1.y - mx);
  v1.z = __expf(v1.z - mx); v1.w = __expf(v1.w - mx);
  float sm = v0.x + v0.y + v0.z + v0.w + v1.x + v1.y + v1.z + v1.w;
#pragma unroll
  for (int off = 32; off >= 1; off >>= 1) sm += __shfl_xor(sm, off);
  __syncthreads();
  if (lane == 0) red[wid] = sm;
  __syncthreads();
  if (tid == 0) red[5] = red[0] + red[1] + red[2] + red[3];
  __syncthreads();
  const float inv = 1.0f / red[5];
  v0.x *= inv; v0.y *= inv; v0.z *= inv; v0.w *= inv;
  v1.x *= inv; v1.y *= inv; v1.z *= inv; v1.w *= inv;
  rowp[tid] = v0;
  rowp[tid + 256] = v1;
}

// ================================ host ================================
extern "C" void kernel_launch(void* const* d_in, const int* in_sizes, int n_in,
                              void* d_out, int out_size, void* d_ws,
                              size_t ws_size, hipStream_t stream) {
  (void)in_sizes; (void)n_in; (void)out_size;
  const int B = 8, N = 2048, D = 512;
  const size_t ND = (size_t)N * D;    // 1,048,576
  const size_t NN = (size_t)N * N;    // 4,194,304
  const float* x = (const float*)d_in[0];
  const float* Wf[3] = {(const float*)d_in[1], (const float*)d_in[3],
                        (const float*)d_in[5]};
  const float* bq = (const float*)d_in[2];
  const float* bk = (const float*)d_in[4];
  const float* bv = (const float*)d_in[6];
  float* out = (float*)d_out;

  char* w = (char*)d_ws;
  auto take = [&](size_t bytes) {
    char* p = w;
    w += (bytes + 255) & ~(size_t)255;
    return p;
  };

  if (ws_size >= 326000000ULL) {
    // ---- Path A: fully batched ----
    u16 *Wh[3], *Wl[3];
    for (int i = 0; i < 3; ++i) {
      Wh[i] = (u16*)take(524288);
      Wl[i] = (u16*)take(524288);
    }
    u16* xh = (u16*)take(2 * B * ND);  u16* xl = (u16*)take(2 * B * ND);
    u16* Qh = (u16*)take(2 * B * ND);  u16* Ql = (u16*)take(2 * B * ND);
    u16* Kh = (u16*)take(2 * B * ND);  u16* Kl = (u16*)take(2 * B * ND);
    u16* Vt = (u16*)take(2 * B * ND);
    float* S = (float*)take(4 * B * NN);
    u16* P = (u16*)take(2 * B * NN);

    split_kernel<<<4096, 256, 0, stream>>>(x, xh, xl, (int)(B * ND / 8));
    for (int i = 0; i < 3; ++i)
      split_kernel<<<128, 256, 0, stream>>>(Wf[i], Wh[i], Wl[i], 32768);
    gemm_qkv2<<<dim3(12, 128), 256, 0, stream>>>(
        xh, xl, Wh[0], Wl[0], Wh[1], Wl[1], Wh[2], bq, bk, bv, Qh, Ql, Kh, Kl,
        Vt, B * N);
    gemm_f32k<3><<<dim3(16, 16, 8), 256, 0, stream>>>(
        Qh, Ql, Kh, Kl, S, 512, 512, 2048, 512, ND, ND, NN);
    softmax_bf16<<<B * N, 256, 0, stream>>>(S, P);
    gemm_f32k<1><<<dim3(4, 16, 8), 256, 0, stream>>>(
        P, nullptr, Vt, nullptr, out, 2048, B * N, 512, 2048, NN, (size_t)N, ND);
  } else if (ws_size >= 208000000ULL) {
    // ---- Path B: batched QKV/PV, per-batch scores+softmax ----
    u16 *Wh[3], *Wl[3];
    for (int i = 0; i < 3; ++i) {
      Wh[i] = (u16*)take(524288);
      Wl[i] = (u16*)take(524288);
    }
    u16* xh = (u16*)take(2 * B * ND);  u16* xl = (u16*)take(2 * B * ND);
    u16* Qh = (u16*)take(2 * B * ND);  u16* Ql = (u16*)take(2 * B * ND);
    u16* Kh = (u16*)take(2 * B * ND);  u16* Kl = (u16*)take(2 * B * ND);
    u16* Vt = (u16*)take(2 * B * ND);
    float* S = (float*)take(4 * NN);
    u16* P = (u16*)take(2 * B * NN);

    split_kernel<<<4096, 256, 0, stream>>>(x, xh, xl, (int)(B * ND / 8));
    for (int i = 0; i < 3; ++i)
      split_kernel<<<128, 256, 0, stream>>>(Wf[i], Wh[i], Wl[i], 32768);
    gemm_qkv2<<<dim3(12, 128), 256, 0, stream>>>(
        xh, xl, Wh[0], Wl[0], Wh[1], Wl[1], Wh[2], bq, bk, bv, Qh, Ql, Kh, Kl,
        Vt, B * N);
    for (int b = 0; b < B; ++b) {
      gemm_f32k<3><<<dim3(16, 16, 1), 256, 0, stream>>>(
          Qh + b * ND, Ql + b * ND, Kh + b * ND, Kl + b * ND, S, 512, 512, 2048,
          512, 0, 0, 0);
      softmax_bf16<<<N, 256, 0, stream>>>(S, P + b * NN);
    }
    gemm_f32k<1><<<dim3(4, 16, 8), 256, 0, stream>>>(
        P, nullptr, Vt, nullptr, out, 2048, B * N, 512, 2048, NN, (size_t)N, ND);
  } else if (ws_size >= 44500000ULL) {
    // ---- Path C: per-batch everything ----
    u16 *Wh[3], *Wl[3];
    for (int i = 0; i < 3; ++i) {
      Wh[i] = (u16*)take(524288);
      Wl[i] = (u16*)take(524288);
    }
    u16* xh = (u16*)take(2 * ND);  u16* xl = (u16*)take(2 * ND);
    u16* Qh = (u16*)take(2 * ND);  u16* Ql = (u16*)take(2 * ND);
    u16* Kh = (u16*)take(2 * ND);  u16* Kl = (u16*)take(2 * ND);
    u16* Vt = (u16*)take(2 * ND);
    float* S = (float*)take(4 * NN);
    u16* P = (u16*)take(2 * NN);

    for (int i = 0; i < 3; ++i)
      split_kernel<<<128, 256, 0, stream>>>(Wf[i], Wh[i], Wl[i], 32768);
    for (int b = 0; b < B; ++b) {
      split_kernel<<<512, 256, 0, stream>>>(x + b * ND, xh, xl, (int)(ND / 8));
      gemm_qkv2<<<dim3(12, 16), 256, 0, stream>>>(
          xh, xl, Wh[0], Wl[0], Wh[1], Wl[1], Wh[2], bq, bk, bv, Qh, Ql, Kh,
          Kl, Vt, N);
      gemm_f32k<3><<<dim3(16, 16, 1), 256, 0, stream>>>(
          Qh, Ql, Kh, Kl, S, 512, 512, 2048, 512, 0, 0, 0);
      softmax_bf16<<<N, 256, 0, stream>>>(S, P);
      gemm_f32k<1><<<dim3(4, 16, 1), 256, 0, stream>>>(
          P, nullptr, Vt, nullptr, out + b * ND, 2048, 2048, 512, 2048, 0, 0, 0);
    }
  } else {
    // ---- fp32 fallback (round-0 path, 29.4 MB) ----
    float* ws = (float*)d_ws;
    float* Q = ws;
    float* Kp = ws + ND;
    float* V = ws + 2 * ND;
    float* S = ws + 3 * ND;
    for (int b = 0; b < B; ++b) {
      const float* xb = x + b * ND;
      float* outb = out + b * ND;
      qkv_leg<<<dim3(8, 32, 3), 256, 0, stream>>>(xb, Wf[0], bq, Wf[1], bk,
                                                  Wf[2], bv, Q, Kp, V);
      gemm_leg<true, false><<<dim3(32, 32), 256, 0, stream>>>(Q, Kp, nullptr, S,
                                                              512, 512, 2048, 512);
      softmax_leg<<<N, 256, 0, stream>>>(S, N);
      gemm_leg<false, false><<<dim3(8, 32), 256, 0, stream>>>(S, V, nullptr,
                                                              outb, 2048, 512,
                                                              512, 2048);
    }
  }
}

// Round 4
// 391.647 us; speedup vs baseline: 4.6389x; 1.2312x over previous
//
#include <hip/hip_runtime.h>

typedef __attribute__((ext_vector_type(8))) short bf16x8;          // 8 bf16 (4 VGPRs)
typedef __attribute__((ext_vector_type(8))) unsigned short u16x8;  // 16B chunk
typedef __attribute__((ext_vector_type(4))) float f32x4;
typedef unsigned short u16;

__device__ __forceinline__ u16 f2bf(float f) {  // round-to-nearest-even bf16
  unsigned u = __float_as_uint(f);
  u += 0x7fffu + ((u >> 16) & 1u);
  return (u16)(u >> 16);
}
__device__ __forceinline__ float bf2f(u16 h) {
  return __uint_as_float((unsigned)h << 16);
}

// Async global->LDS DMA, 16B per lane. LDS dest semantics: wave-uniform base +
// lane*16 (m104) — our per-lane pointers are exactly base + lane*16B.
__device__ __forceinline__ void gl_lds16(const u16* g, u16* l) {
  __builtin_amdgcn_global_load_lds(
      (const __attribute__((address_space(1))) void*)g,
      (__attribute__((address_space(3))) void*)l, 16, 0, 0);
}

// ---------------- fp32 -> bf16 hi/lo split (elementwise) ----------------
__global__ __launch_bounds__(256) void split_kernel(const float* __restrict__ in,
                                                    u16* __restrict__ hi,
                                                    u16* __restrict__ lo, int n8) {
  int t = blockIdx.x * 256 + threadIdx.x;
  if (t >= n8) return;
  const float4* p = (const float4*)in;
  float4 a = p[2 * t], b = p[2 * t + 1];
  float v[8] = {a.x, a.y, a.z, a.w, b.x, b.y, b.z, b.w};
  u16x8 h, l;
#pragma unroll
  for (int i = 0; i < 8; ++i) {
    u16 hh = f2bf(v[i]);
    h[i] = hh;
    l[i] = f2bf(v[i] - bf2f(hh));
  }
  *(u16x8*)(hi + (size_t)t * 8) = h;
  *(u16x8*)(lo + (size_t)t * 8) = l;
}

// ---------------- MFMA GEMM core (global_load_lds staging) ----------------
// C[m,n] = sum_k A[m,k]*B[n,k], both operands row-major [free][k] bf16.
// BM=BN=128, BK=32, 256 threads (4 waves), 64x64 per wave via 4x4 mfma
// 16x16x32. LDS per matrix: [row 0..127][32 u16] unpadded (8 KB), staged by
// 2 global_load_lds-dwordx4 per wave per matrix per k-step.
// PASSES=3: A,B as hi/lo pairs; hh + hl + lh MFMA passes (~fp32 accuracy).
template <int PASSES>
__device__ __forceinline__ void mfma_core(u16* s, const u16* __restrict__ Ah,
                                          const u16* __restrict__ Al,
                                          const u16* __restrict__ Bh,
                                          const u16* __restrict__ Bl,
                                          int lda, int ldb, int Kdim,
                                          int m0, int n0, f32x4 acc[4][4]) {
  const int tid = threadIdx.x;
  const int l = tid & 63, w = tid >> 6;
  const int wm = w >> 1, wn = w & 1;
  const int quad = l >> 4, l15 = l & 15;
  const int srow = w * 32 + (l >> 2);  // staging row (and +16)
  const int skc = (l & 3) * 8;         // staging k offset (u16)

  u16* sA = s;
  u16* sB = s + 4096;
  u16* sAl = s + 8192;
  u16* sBl = s + 12288;

  const u16* gA0 = Ah + (size_t)(m0 + srow) * lda + skc;
  const u16* gB0 = Bh + (size_t)(n0 + srow) * ldb + skc;
  const u16* gAl0 = nullptr;
  const u16* gBl0 = nullptr;
  if (PASSES == 3) {
    gAl0 = Al + (size_t)(m0 + srow) * lda + skc;
    gBl0 = Bl + (size_t)(n0 + srow) * ldb + skc;
  }
  u16* lA0 = sA + srow * 32 + skc;  // == sA + w*1024 + lane*8 (16B/lane)
  u16* lB0 = sB + srow * 32 + skc;
  u16* lAl0 = sAl + srow * 32 + skc;
  u16* lBl0 = sBl + srow * 32 + skc;
  const size_t a16 = (size_t)16 * lda, b16 = (size_t)16 * ldb;

  const int afrag = (wm * 64 + l15) * 32 + quad * 8;  // u16 idx; +i*512 rows
  const int bfrag = (wn * 64 + l15) * 32 + quad * 8;

  for (int k0 = 0; k0 < Kdim; k0 += 32) {
    __syncthreads();  // previous tile's ds_reads done before DMA overwrite
    gl_lds16(gA0 + k0, lA0);
    gl_lds16(gA0 + k0 + a16, lA0 + 512);
    gl_lds16(gB0 + k0, lB0);
    gl_lds16(gB0 + k0 + b16, lB0 + 512);
    if (PASSES == 3) {
      gl_lds16(gAl0 + k0, lAl0);
      gl_lds16(gAl0 + k0 + a16, lAl0 + 512);
      gl_lds16(gBl0 + k0, lBl0);
      gl_lds16(gBl0 + k0 + b16, lBl0 + 512);
    }
    __syncthreads();  // drains vmcnt (DMA visible)

    bf16x8 fah[4], fbh[4];
#pragma unroll
    for (int i = 0; i < 4; ++i) fah[i] = *(const bf16x8*)(sA + afrag + i * 512);
#pragma unroll
    for (int j = 0; j < 4; ++j) fbh[j] = *(const bf16x8*)(sB + bfrag + j * 512);
#pragma unroll
    for (int i = 0; i < 4; ++i)
#pragma unroll
      for (int j = 0; j < 4; ++j)
        acc[i][j] = __builtin_amdgcn_mfma_f32_16x16x32_bf16(fah[i], fbh[j],
                                                            acc[i][j], 0, 0, 0);
    if (PASSES == 3) {
      bf16x8 fal[4], fbl[4];
#pragma unroll
      for (int i = 0; i < 4; ++i)
        fal[i] = *(const bf16x8*)(sAl + afrag + i * 512);
#pragma unroll
      for (int j = 0; j < 4; ++j)
        fbl[j] = *(const bf16x8*)(sBl + bfrag + j * 512);
#pragma unroll
      for (int i = 0; i < 4; ++i)
#pragma unroll
        for (int j = 0; j < 4; ++j) {
          acc[i][j] = __builtin_amdgcn_mfma_f32_16x16x32_bf16(fah[i], fbl[j],
                                                              acc[i][j], 0, 0, 0);
          acc[i][j] = __builtin_amdgcn_mfma_f32_16x16x32_bf16(fal[i], fbh[j],
                                                              acc[i][j], 0, 0, 0);
        }
    }
  }
}

// C/D layout (m89-verified): row m = quad*4 + reg, col n = lane&15.
template <int PASSES>
__global__ __launch_bounds__(256, 2) void gemm_f32k(
    const u16* __restrict__ Ah, const u16* __restrict__ Al,
    const u16* __restrict__ Bh, const u16* __restrict__ Bl,
    float* __restrict__ C, int lda, int ldb, int ldc, int Kdim,
    size_t aStride, size_t bStride, size_t cStride) {
  __shared__ u16 s[PASSES == 3 ? 16384 : 8192];
  const int z = blockIdx.z;
  f32x4 acc[4][4];
  const f32x4 zero = {0.0f, 0.0f, 0.0f, 0.0f};
#pragma unroll
  for (int i = 0; i < 4; ++i)
#pragma unroll
    for (int j = 0; j < 4; ++j) acc[i][j] = zero;
  mfma_core<PASSES>(s, Ah + z * aStride, (PASSES == 3) ? Al + z * aStride : Al,
                    Bh + z * bStride, (PASSES == 3) ? Bl + z * bStride : Bl,
                    lda, ldb, Kdim, blockIdx.y * 128, blockIdx.x * 128, acc);
  float* Cz = C + z * cStride;
  const int lane = threadIdx.x & 63;
  const int wave = threadIdx.x >> 6;
  const int quad = lane >> 4, l15 = lane & 15;
  const int em = (int)blockIdx.y * 128 + (wave >> 1) * 64 + quad * 4;
  const int en = (int)blockIdx.x * 128 + (wave & 1) * 64 + l15;
#pragma unroll
  for (int i = 0; i < 4; ++i)
#pragma unroll
    for (int r = 0; r < 4; ++r) {
      size_t row = (size_t)(em + i * 16 + r) * ldc;
#pragma unroll
      for (int j = 0; j < 4; ++j) Cz[row + en + j * 16] = acc[i][j][r];
    }
}

// QKV: blockIdx.x = (z<<2)|ntile so the 12 blocks sharing the same x-rows are
// consecutive (L3 temporal reuse of x). z=0 Q (hi/lo out, 3-pass), z=1 K
// (hi/lo out, 3-pass), z=2 V (1-pass, transposed bf16 out Vt[e][m]).
__global__ __launch_bounds__(256, 2) void gemm_qkv2(
    const u16* __restrict__ xh, const u16* __restrict__ xl,
    const u16* __restrict__ Wqh, const u16* __restrict__ Wql,
    const u16* __restrict__ Wkh, const u16* __restrict__ Wkl,
    const u16* __restrict__ Wvh, const float* __restrict__ bq,
    const float* __restrict__ bk, const float* __restrict__ bv,
    u16* __restrict__ Qh, u16* __restrict__ Ql, u16* __restrict__ Kh,
    u16* __restrict__ Kl, u16* __restrict__ Vt, int ldvt) {
  __shared__ u16 s[16384];
  const int z = blockIdx.x >> 2;
  const int n0 = (blockIdx.x & 3) * 128;
  const int m0 = blockIdx.y * 128;
  f32x4 acc[4][4];
  const f32x4 zero = {0.0f, 0.0f, 0.0f, 0.0f};
#pragma unroll
  for (int i = 0; i < 4; ++i)
#pragma unroll
    for (int j = 0; j < 4; ++j) acc[i][j] = zero;

  if (z == 2) {
    mfma_core<1>(s, xh, nullptr, Wvh, nullptr, 512, 512, 512, m0, n0, acc);
  } else if (z == 1) {
    mfma_core<3>(s, xh, xl, Wkh, Wkl, 512, 512, 512, m0, n0, acc);
  } else {
    mfma_core<3>(s, xh, xl, Wqh, Wql, 512, 512, 512, m0, n0, acc);
  }

  const float* bias = (z == 0) ? bq : (z == 1) ? bk : bv;
  const int lane = threadIdx.x & 63;
  const int wave = threadIdx.x >> 6;
  const int quad = lane >> 4, l15 = lane & 15;
  const int em = m0 + (wave >> 1) * 64 + quad * 4;
  const int en = n0 + (wave & 1) * 64 + l15;
  float bj[4];
#pragma unroll
  for (int j = 0; j < 4; ++j) bj[j] = bias[en + j * 16];
  if (z < 2) {
    u16* Oh = (z == 0) ? Qh : Kh;
    u16* Ol = (z == 0) ? Ql : Kl;
#pragma unroll
    for (int i = 0; i < 4; ++i)
#pragma unroll
      for (int r = 0; r < 4; ++r) {
        size_t row = (size_t)(em + i * 16 + r) * 512;
#pragma unroll
        for (int j = 0; j < 4; ++j) {
          float v = acc[i][j][r] + bj[j];
          u16 h = f2bf(v);
          Oh[row + en + j * 16] = h;
          Ol[row + en + j * 16] = f2bf(v - bf2f(h));
        }
      }
  } else {
#pragma unroll
    for (int i = 0; i < 4; ++i)
#pragma unroll
      for (int r = 0; r < 4; ++r) {
        int m = em + i * 16 + r;
#pragma unroll
        for (int j = 0; j < 4; ++j) {
          float v = acc[i][j][r] + bj[j];
          Vt[(size_t)(en + j * 16) * ldvt + m] = f2bf(v);
        }
      }
  }
}

// ------- softmax row 2048, IN-PLACE: fp32 row -> bf16 P in the row's first
// half. Block owns its row; loads complete before the first __syncthreads of
// the reduction, stores happen after the last -> no intra-row WAR hazard.
__global__ __launch_bounds__(256) void softmax_inplace(float* __restrict__ S) {
  __shared__ float red[8];
  const int tid = threadIdx.x;
  const size_t row = blockIdx.x;
  const float4* src = (const float4*)(S + row * 2048);
  float4 v0 = src[2 * tid], v1 = src[2 * tid + 1];

  float mx = fmaxf(fmaxf(fmaxf(v0.x, v0.y), fmaxf(v0.z, v0.w)),
                   fmaxf(fmaxf(v1.x, v1.y), fmaxf(v1.z, v1.w)));
#pragma unroll
  for (int off = 32; off >= 1; off >>= 1) mx = fmaxf(mx, __shfl_xor(mx, off));
  const int wid = tid >> 6, lane = tid & 63;
  if (lane == 0) red[wid] = mx;
  __syncthreads();
  if (tid == 0) red[4] = fmaxf(fmaxf(red[0], red[1]), fmaxf(red[2], red[3]));
  __syncthreads();
  mx = red[4];

  v0.x = __expf(v0.x - mx); v0.y = __expf(v0.y - mx);
  v0.z = __expf(v0.z - mx); v0.w = __expf(v0.w - mx);
  v1.x = __expf(v1.x - mx); v1.y = __expf(v1.y - mx);
  v1.z = __expf(v1.z - mx); v1.w = __expf(v1.w - mx);

  float sm = v0.x + v0.y + v0.z + v0.w + v1.x + v1.y + v1.z + v1.w;
#pragma unroll
  for (int off = 32; off >= 1; off >>= 1) sm += __shfl_xor(sm, off);
  __syncthreads();
  if (lane == 0) red[wid] = sm;
  __syncthreads();
  if (tid == 0) red[5] = red[0] + red[1] + red[2] + red[3];
  __syncthreads();
  const float inv = 1.0f / red[5];

  u16x8 o;
  o[0] = f2bf(v0.x * inv); o[1] = f2bf(v0.y * inv);
  o[2] = f2bf(v0.z * inv); o[3] = f2bf(v0.w * inv);
  o[4] = f2bf(v1.x * inv); o[5] = f2bf(v1.y * inv);
  o[6] = f2bf(v1.z * inv); o[7] = f2bf(v1.w * inv);
  *(u16x8*)((u16*)S + row * 4096 + tid * 8) = o;
}

// softmax fp32 -> separate bf16 P (Path B)
__global__ __launch_bounds__(256) void softmax_bf16(const float* __restrict__ S,
                                                    u16* __restrict__ P) {
  __shared__ float red[8];
  const int tid = threadIdx.x;
  const float4* src = (const float4*)(S + (size_t)blockIdx.x * 2048);
  float4 v0 = src[2 * tid], v1 = src[2 * tid + 1];

  float mx = fmaxf(fmaxf(fmaxf(v0.x, v0.y), fmaxf(v0.z, v0.w)),
                   fmaxf(fmaxf(v1.x, v1.y), fmaxf(v1.z, v1.w)));
#pragma unroll
  for (int off = 32; off >= 1; off >>= 1) mx = fmaxf(mx, __shfl_xor(mx, off));
  const int wid = tid >> 6, lane = tid & 63;
  if (lane == 0) red[wid] = mx;
  __syncthreads();
  if (tid == 0) red[4] = fmaxf(fmaxf(red[0], red[1]), fmaxf(red[2], red[3]));
  __syncthreads();
  mx = red[4];

  v0.x = __expf(v0.x - mx); v0.y = __expf(v0.y - mx);
  v0.z = __expf(v0.z - mx); v0.w = __expf(v0.w - mx);
  v1.x = __expf(v1.x - mx); v1.y = __expf(v1.y - mx);
  v1.z = __expf(v1.z - mx); v1.w = __expf(v1.w - mx);

  float sm = v0.x + v0.y + v0.z + v0.w + v1.x + v1.y + v1.z + v1.w;
#pragma unroll
  for (int off = 32; off >= 1; off >>= 1) sm += __shfl_xor(sm, off);
  __syncthreads();
  if (lane == 0) red[wid] = sm;
  __syncthreads();
  if (tid == 0) red[5] = red[0] + red[1] + red[2] + red[3];
  __syncthreads();
  const float inv = 1.0f / red[5];

  u16x8 o;
  o[0] = f2bf(v0.x * inv); o[1] = f2bf(v0.y * inv);
  o[2] = f2bf(v0.z * inv); o[3] = f2bf(v0.w * inv);
  o[4] = f2bf(v1.x * inv); o[5] = f2bf(v1.y * inv);
  o[6] = f2bf(v1.z * inv); o[7] = f2bf(v1.w * inv);
  *(u16x8*)(P + (size_t)blockIdx.x * 2048 + tid * 8) = o;
}

// ================= fp32 fallback (round-0, proven; used only if ws tiny) ====
#define LTILE_M 64
#define LTILE_N 64
#define LTILE_K 32
template <bool B_NT, bool HAS_BIAS>
__device__ __forceinline__ void gemm_body_leg(const float* __restrict__ A,
                                              const float* __restrict__ Bm,
                                              const float* __restrict__ bias,
                                              float* __restrict__ C, int lda,
                                              int ldb, int ldc, int Kdim) {
  __shared__ float As[LTILE_K][LTILE_M + 4];
  __shared__ float Bs[LTILE_K][LTILE_N + 4];
  const int tid = threadIdx.x;
  const int tx = tid & 15, ty = tid >> 4;
  const int m0 = blockIdx.y * LTILE_M, n0 = blockIdx.x * LTILE_N;
  const int am = tid >> 3, ak = (tid & 7) << 2;
  const int bk_ = tid >> 4, bn = (tid & 15) << 2;
  float acc[4][4] = {};
  for (int k0 = 0; k0 < Kdim; k0 += LTILE_K) {
    float4 a0 = *(const float4*)(A + (size_t)(m0 + am) * lda + k0 + ak);
    float4 a1 = *(const float4*)(A + (size_t)(m0 + am + 32) * lda + k0 + ak);
    float4 b0, b1;
    if (B_NT) {
      b0 = *(const float4*)(Bm + (size_t)(n0 + am) * ldb + k0 + ak);
      b1 = *(const float4*)(Bm + (size_t)(n0 + am + 32) * ldb + k0 + ak);
    } else {
      b0 = *(const float4*)(Bm + (size_t)(k0 + bk_) * ldb + n0 + bn);
      b1 = *(const float4*)(Bm + (size_t)(k0 + bk_ + 16) * ldb + n0 + bn);
    }
    __syncthreads();
    As[ak + 0][am] = a0.x; As[ak + 1][am] = a0.y;
    As[ak + 2][am] = a0.z; As[ak + 3][am] = a0.w;
    As[ak + 0][am + 32] = a1.x; As[ak + 1][am + 32] = a1.y;
    As[ak + 2][am + 32] = a1.z; As[ak + 3][am + 32] = a1.w;
    if (B_NT) {
      Bs[ak + 0][am] = b0.x; Bs[ak + 1][am] = b0.y;
      Bs[ak + 2][am] = b0.z; Bs[ak + 3][am] = b0.w;
      Bs[ak + 0][am + 32] = b1.x; Bs[ak + 1][am + 32] = b1.y;
      Bs[ak + 2][am + 32] = b1.z; Bs[ak + 3][am + 32] = b1.w;
    } else {
      *(float4*)&Bs[bk_][bn] = b0;
      *(float4*)&Bs[bk_ + 16][bn] = b1;
    }
    __syncthreads();
#pragma unroll
    for (int kk = 0; kk < LTILE_K; ++kk) {
      float4 av = *(const float4*)&As[kk][ty << 2];
      float4 bv4 = *(const float4*)&Bs[kk][tx << 2];
      acc[0][0] += av.x * bv4.x; acc[0][1] += av.x * bv4.y;
      acc[0][2] += av.x * bv4.z; acc[0][3] += av.x * bv4.w;
      acc[1][0] += av.y * bv4.x; acc[1][1] += av.y * bv4.y;
      acc[1][2] += av.y * bv4.z; acc[1][3] += av.y * bv4.w;
      acc[2][0] += av.z * bv4.x; acc[2][1] += av.z * bv4.y;
      acc[2][2] += av.z * bv4.z; acc[2][3] += av.z * bv4.w;
      acc[3][0] += av.w * bv4.x; acc[3][1] += av.w * bv4.y;
      acc[3][2] += av.w * bv4.z; acc[3][3] += av.w * bv4.w;
    }
  }
  float4 badd = {0.0f, 0.0f, 0.0f, 0.0f};
  if (HAS_BIAS) badd = *(const float4*)(bias + n0 + (tx << 2));
#pragma unroll
  for (int r = 0; r < 4; ++r) {
    float4 o;
    o.x = acc[r][0] + badd.x; o.y = acc[r][1] + badd.y;
    o.z = acc[r][2] + badd.z; o.w = acc[r][3] + badd.w;
    *(float4*)(C + (size_t)(m0 + (ty << 2) + r) * ldc + n0 + (tx << 2)) = o;
  }
}
template <bool B_NT, bool HAS_BIAS>
__global__ __launch_bounds__(256, 4) void gemm_leg(const float* A, const float* Bm,
                                                   const float* bias, float* C,
                                                   int lda, int ldb, int ldc,
                                                   int Kdim) {
  gemm_body_leg<B_NT, HAS_BIAS>(A, Bm, bias, C, lda, ldb, ldc, Kdim);
}
__global__ __launch_bounds__(256, 4) void qkv_leg(
    const float* x, const float* Wq, const float* bq, const float* Wk,
    const float* bk, const float* Wv, const float* bv, float* Q, float* K,
    float* V) {
  const float *W, *bias;
  float* C;
  if (blockIdx.z == 0) { W = Wq; bias = bq; C = Q; }
  else if (blockIdx.z == 1) { W = Wk; bias = bk; C = K; }
  else { W = Wv; bias = bv; C = V; }
  gemm_body_leg<true, true>(x, W, bias, C, 512, 512, 512, 512);
}
__global__ __launch_bounds__(256) void softmax_leg(float* S, int ncols) {
  __shared__ float red[8];
  float4* rowp = (float4*)(S + (size_t)blockIdx.x * ncols);
  const int tid = threadIdx.x;
  float4 v0 = rowp[tid], v1 = rowp[tid + 256];
  float mx = fmaxf(fmaxf(fmaxf(v0.x, v0.y), fmaxf(v0.z, v0.w)),
                   fmaxf(fmaxf(v1.x, v1.y), fmaxf(v1.z, v1.w)));
#pragma unroll
  for (int off = 32; off >= 1; off >>= 1) mx = fmaxf(mx, __shfl_xor(mx, off));
  const int wid = tid >> 6, lane = tid & 63;
  if (lane == 0) red[wid] = mx;
  __syncthreads();
  if (tid == 0) red[4] = fmaxf(fmaxf(red[0], red[1]), fmaxf(red[2], red[3]));
  __syncthreads();
  mx = red[4];
  v0.x = __expf(v0.x - mx); v0.y = __expf(v0.y - mx);
  v0.z = __expf(v0.z - mx); v0.w = __expf(v0.w - mx);
  v1.x = __expf(v1.x - mx); v1.y = __expf(v1.y - mx);
  v1.z = __expf(v1.z - mx); v1.w = __expf(v1.w - mx);
  float sm = v0.x + v0.y + v0.z + v0.w + v1.x + v1.y + v1.z + v1.w;
#pragma unroll
  for (int off = 32; off >= 1; off >>= 1) sm += __shfl_xor(sm, off);
  __syncthreads();
  if (lane == 0) red[wid] = sm;
  __syncthreads();
  if (tid == 0) red[5] = red[0] + red[1] + red[2] + red[3];
  __syncthreads();
  const float inv = 1.0f / red[5];
  v0.x *= inv; v0.y *= inv; v0.z *= inv; v0.w *= inv;
  v1.x *= inv; v1.y *= inv; v1.z *= inv; v1.w *= inv;
  rowp[tid] = v0;
  rowp[tid + 256] = v1;
}

// ================================ host ================================
extern "C" void kernel_launch(void* const* d_in, const int* in_sizes, int n_in,
                              void* d_out, int out_size, void* d_ws,
                              size_t ws_size, hipStream_t stream) {
  (void)in_sizes; (void)n_in; (void)out_size;
  const int B = 8, N = 2048, D = 512;
  const size_t ND = (size_t)N * D;    // 1,048,576
  const size_t NN = (size_t)N * N;    // 4,194,304
  const float* x = (const float*)d_in[0];
  const float* Wf[3] = {(const float*)d_in[1], (const float*)d_in[3],
                        (const float*)d_in[5]};
  const float* bq = (const float*)d_in[2];
  const float* bk = (const float*)d_in[4];
  const float* bv = (const float*)d_in[6];
  float* out = (float*)d_out;

  char* w = (char*)d_ws;
  auto take = [&](size_t bytes) {
    char* p = w;
    w += (bytes + 255) & ~(size_t)255;
    return p;
  };

  if (ws_size >= 218000000ULL) {
    // ---- Path A2: fully batched; P written in place over S; S overlaps the
    // x hi/lo region (dead after QKV). Packed total ~217.1 MB.
    u16 *Wh[3], *Wl[3];
    for (int i = 0; i < 3; ++i) {
      Wh[i] = (u16*)take(524288);
      Wl[i] = (u16*)take(524288);
    }
    u16* Qh = (u16*)take(2 * B * ND);  // 16 MB each
    u16* Ql = (u16*)take(2 * B * ND);
    u16* Kh = (u16*)take(2 * B * ND);
    u16* Kl = (u16*)take(2 * B * ND);
    u16* Vt = (u16*)take(2 * B * ND);
    char* sBase = w;                       // S region starts here...
    float* S = (float*)sBase;              // 134.2 MB
    u16* xh = (u16*)take(2 * B * ND);      // ...x hi/lo live inside S's first
    u16* xl = (u16*)take(2 * B * ND);      // 32 MB, dead once QKV completes.

    split_kernel<<<4096, 256, 0, stream>>>(x, xh, xl, (int)(B * ND / 8));
    for (int i = 0; i < 3; ++i)
      split_kernel<<<128, 256, 0, stream>>>(Wf[i], Wh[i], Wl[i], 32768);
    gemm_qkv2<<<dim3(12, 128), 256, 0, stream>>>(
        xh, xl, Wh[0], Wl[0], Wh[1], Wl[1], Wh[2], bq, bk, bv, Qh, Ql, Kh, Kl,
        Vt, B * N);
    // scores: one dispatch, all batches
    gemm_f32k<3><<<dim3(16, 16, 8), 256, 0, stream>>>(
        Qh, Ql, Kh, Kl, S, 512, 512, 2048, 512, ND, ND, NN);
    // softmax: one dispatch, in-place bf16 P (row stride 4096 u16)
    softmax_inplace<<<B * N, 256, 0, stream>>>(S);
    // PV: P = (u16*)S, lda=4096 u16, batch stride 2*NN u16
    gemm_f32k<1><<<dim3(4, 16, 8), 256, 0, stream>>>(
        (const u16*)S, nullptr, Vt, nullptr, out, 4096, B * N, 512, 2048,
        2 * NN, (size_t)N, ND);
  } else if (ws_size >= 208000000ULL) {
    // ---- Path B: batched QKV/PV, per-batch scores+softmax ----
    u16 *Wh[3], *Wl[3];
    for (int i = 0; i < 3; ++i) {
      Wh[i] = (u16*)take(524288);
      Wl[i] = (u16*)take(524288);
    }
    u16* xh = (u16*)take(2 * B * ND);  u16* xl = (u16*)take(2 * B * ND);
    u16* Qh = (u16*)take(2 * B * ND);  u16* Ql = (u16*)take(2 * B * ND);
    u16* Kh = (u16*)take(2 * B * ND);  u16* Kl = (u16*)take(2 * B * ND);
    u16* Vt = (u16*)take(2 * B * ND);
    float* S = (float*)take(4 * NN);
    u16* P = (u16*)take(2 * B * NN);

    split_kernel<<<4096, 256, 0, stream>>>(x, xh, xl, (int)(B * ND / 8));
    for (int i = 0; i < 3; ++i)
      split_kernel<<<128, 256, 0, stream>>>(Wf[i], Wh[i], Wl[i], 32768);
    gemm_qkv2<<<dim3(12, 128), 256, 0, stream>>>(
        xh, xl, Wh[0], Wl[0], Wh[1], Wl[1], Wh[2], bq, bk, bv, Qh, Ql, Kh, Kl,
        Vt, B * N);
    for (int b = 0; b < B; ++b) {
      gemm_f32k<3><<<dim3(16, 16, 1), 256, 0, stream>>>(
          Qh + b * ND, Ql + b * ND, Kh + b * ND, Kl + b * ND, S, 512, 512, 2048,
          512, 0, 0, 0);
      softmax_bf16<<<N, 256, 0, stream>>>(S, P + b * NN);
    }
    gemm_f32k<1><<<dim3(4, 16, 8), 256, 0, stream>>>(
        P, nullptr, Vt, nullptr, out, 2048, B * N, 512, 2048, NN, (size_t)N, ND);
  } else if (ws_size >= 44500000ULL) {
    // ---- Path C: per-batch everything ----
    u16 *Wh[3], *Wl[3];
    for (int i = 0; i < 3; ++i) {
      Wh[i] = (u16*)take(524288);
      Wl[i] = (u16*)take(524288);
    }
    u16* xh = (u16*)take(2 * ND);  u16* xl = (u16*)take(2 * ND);
    u16* Qh = (u16*)take(2 * ND);  u16* Ql = (u16*)take(2 * ND);
    u16* Kh = (u16*)take(2 * ND);  u16* Kl = (u16*)take(2 * ND);
    u16* Vt = (u16*)take(2 * ND);
    float* S = (float*)take(4 * NN);
    u16* P = (u16*)take(2 * NN);

    for (int i = 0; i < 3; ++i)
      split_kernel<<<128, 256, 0, stream>>>(Wf[i], Wh[i], Wl[i], 32768);
    for (int b = 0; b < B; ++b) {
      split_kernel<<<512, 256, 0, stream>>>(x + b * ND, xh, xl, (int)(ND / 8));
      gemm_qkv2<<<dim3(12, 16), 256, 0, stream>>>(
          xh, xl, Wh[0], Wl[0], Wh[1], Wl[1], Wh[2], bq, bk, bv, Qh, Ql, Kh,
          Kl, Vt, N);
      gemm_f32k<3><<<dim3(16, 16, 1), 256, 0, stream>>>(
          Qh, Ql, Kh, Kl, S, 512, 512, 2048, 512, 0, 0, 0);
      softmax_bf16<<<N, 256, 0, stream>>>(S, P);
      gemm_f32k<1><<<dim3(4, 16, 1), 256, 0, stream>>>(
          P, nullptr, Vt, nullptr, out + b * ND, 2048, 2048, 512, 2048, 0, 0, 0);
    }
  } else {
    // ---- fp32 fallback (round-0 path, 29.4 MB) ----
    float* ws = (float*)d_ws;
    float* Q = ws;
    float* Kp = ws + ND;
    float* V = ws + 2 * ND;
    float* S = ws + 3 * ND;
    for (int b = 0; b < B; ++b) {
      const float* xb = x + b * ND;
      float* outb = out + b * ND;
      qkv_leg<<<dim3(8, 32, 3), 256, 0, stream>>>(xb, Wf[0], bq, Wf[1], bk,
                                                  Wf[2], bv, Q, Kp, V);
      gemm_leg<true, false><<<dim3(32, 32), 256, 0, stream>>>(Q, Kp, nullptr, S,
                                                              512, 512, 2048, 512);
      softmax_leg<<<N, 256, 0, stream>>>(S, N);
      gemm_leg<false, false><<<dim3(8, 32), 256, 0, stream>>>(S, V, nullptr,
                                                              outb, 2048, 512,
                                                              512, 2048);
    }
  }
}

// Round 5
// 325.602 us; speedup vs baseline: 5.5798x; 1.2028x over previous
//
#include <hip/hip_runtime.h>

typedef __attribute__((ext_vector_type(8))) _Float16 f16x8;        // 8 fp16 (4 VGPRs)
typedef __attribute__((ext_vector_type(8))) unsigned short u16x8;  // 16B chunk
typedef __attribute__((ext_vector_type(4))) float f32x4;
typedef unsigned short u16;

__device__ __forceinline__ u16 f2h(float f) {  // RNE fp16
  _Float16 h = (_Float16)f;
  return __builtin_bit_cast(u16, h);
}
__device__ __forceinline__ float h2f(u16 u) {
  return (float)__builtin_bit_cast(_Float16, u);
}

// Async global->LDS DMA, 16B per lane (dest = wave-uniform base + lane*16).
__device__ __forceinline__ void gl_lds16(const u16* g, u16* l) {
  __builtin_amdgcn_global_load_lds(
      (const __attribute__((address_space(1))) void*)g,
      (__attribute__((address_space(3))) void*)l, 16, 0, 0);
}

// ---------------- fp32 -> fp16 hi(/lo residual) split ----------------
template <bool LO>
__global__ __launch_bounds__(256) void split_h(const float* __restrict__ in,
                                               u16* __restrict__ hi,
                                               u16* __restrict__ lo, int n8) {
  int t = blockIdx.x * 256 + threadIdx.x;
  if (t >= n8) return;
  const float4* p = (const float4*)in;
  float4 a = p[2 * t], b = p[2 * t + 1];
  float v[8] = {a.x, a.y, a.z, a.w, b.x, b.y, b.z, b.w};
  u16x8 h, l;
#pragma unroll
  for (int i = 0; i < 8; ++i) {
    u16 hh = f2h(v[i]);
    h[i] = hh;
    if (LO) l[i] = f2h(v[i] - h2f(hh));
  }
  *(u16x8*)(hi + (size_t)t * 8) = h;
  if (LO) *(u16x8*)(lo + (size_t)t * 8) = l;
}

// ---------------- MFMA GEMM core (fp16, global_load_lds staging) ----------
// C[m,n] = sum_k A[m,k]*B[n,k], operands row-major [free][k] fp16.
// BM=BN=128, BK=32, 256 threads (4 waves), 64x64/wave via 4x4 mfma 16x16x32.
// LDS per matrix: [row 0..127][32 u16] unpadded (8 KB), 2 DMA-dwordx4 per
// wave per matrix per k-step. PASSES=3: A,B hi/lo pairs, hh+hl+lh (~fp32).
template <int PASSES>
__device__ __forceinline__ void mfma_core(u16* s, const u16* __restrict__ Ah,
                                          const u16* __restrict__ Al,
                                          const u16* __restrict__ Bh,
                                          const u16* __restrict__ Bl,
                                          int lda, int ldb, int Kdim,
                                          int m0, int n0, f32x4 acc[4][4]) {
  const int tid = threadIdx.x;
  const int l = tid & 63, w = tid >> 6;
  const int wm = w >> 1, wn = w & 1;
  const int quad = l >> 4, l15 = l & 15;
  const int srow = w * 32 + (l >> 2);  // staging row (and +16)
  const int skc = (l & 3) * 8;         // staging k offset (u16)

  u16* sA = s;
  u16* sB = s + 4096;
  u16* sAl = s + 8192;
  u16* sBl = s + 12288;

  const u16* gA0 = Ah + (size_t)(m0 + srow) * lda + skc;
  const u16* gB0 = Bh + (size_t)(n0 + srow) * ldb + skc;
  const u16* gAl0 = nullptr;
  const u16* gBl0 = nullptr;
  if (PASSES == 3) {
    gAl0 = Al + (size_t)(m0 + srow) * lda + skc;
    gBl0 = Bl + (size_t)(n0 + srow) * ldb + skc;
  }
  u16* lA0 = sA + srow * 32 + skc;
  u16* lB0 = sB + srow * 32 + skc;
  u16* lAl0 = sAl + srow * 32 + skc;
  u16* lBl0 = sBl + srow * 32 + skc;
  const size_t a16 = (size_t)16 * lda, b16 = (size_t)16 * ldb;

  const int afrag = (wm * 64 + l15) * 32 + quad * 8;  // u16 idx; +i*512 rows
  const int bfrag = (wn * 64 + l15) * 32 + quad * 8;

  for (int k0 = 0; k0 < Kdim; k0 += 32) {
    __syncthreads();  // previous tile's ds_reads done before DMA overwrite
    gl_lds16(gA0 + k0, lA0);
    gl_lds16(gA0 + k0 + a16, lA0 + 512);
    gl_lds16(gB0 + k0, lB0);
    gl_lds16(gB0 + k0 + b16, lB0 + 512);
    if (PASSES == 3) {
      gl_lds16(gAl0 + k0, lAl0);
      gl_lds16(gAl0 + k0 + a16, lAl0 + 512);
      gl_lds16(gBl0 + k0, lBl0);
      gl_lds16(gBl0 + k0 + b16, lBl0 + 512);
    }
    __syncthreads();  // drains vmcnt (DMA visible)

    f16x8 fah[4], fbh[4];
#pragma unroll
    for (int i = 0; i < 4; ++i) fah[i] = *(const f16x8*)(sA + afrag + i * 512);
#pragma unroll
    for (int j = 0; j < 4; ++j) fbh[j] = *(const f16x8*)(sB + bfrag + j * 512);
#pragma unroll
    for (int i = 0; i < 4; ++i)
#pragma unroll
      for (int j = 0; j < 4; ++j)
        acc[i][j] = __builtin_amdgcn_mfma_f32_16x16x32_f16(fah[i], fbh[j],
                                                           acc[i][j], 0, 0, 0);
    if (PASSES == 3) {
      f16x8 fal[4], fbl[4];
#pragma unroll
      for (int i = 0; i < 4; ++i)
        fal[i] = *(const f16x8*)(sAl + afrag + i * 512);
#pragma unroll
      for (int j = 0; j < 4; ++j)
        fbl[j] = *(const f16x8*)(sBl + bfrag + j * 512);
#pragma unroll
      for (int i = 0; i < 4; ++i)
#pragma unroll
        for (int j = 0; j < 4; ++j) {
          acc[i][j] = __builtin_amdgcn_mfma_f32_16x16x32_f16(fah[i], fbl[j],
                                                             acc[i][j], 0, 0, 0);
          acc[i][j] = __builtin_amdgcn_mfma_f32_16x16x32_f16(fal[i], fbh[j],
                                                             acc[i][j], 0, 0, 0);
        }
    }
  }
}

// C/D layout (m89-verified): row m = quad*4 + reg, col n = lane&15.
template <int PASSES>
__global__ __launch_bounds__(256, 2) void gemm_f32k(
    const u16* __restrict__ Ah, const u16* __restrict__ Al,
    const u16* __restrict__ Bh, const u16* __restrict__ Bl,
    float* __restrict__ C, int lda, int ldb, int ldc, int Kdim,
    size_t aStride, size_t bStride, size_t cStride) {
  __shared__ u16 s[PASSES == 3 ? 16384 : 8192];
  const int z = blockIdx.z;
  f32x4 acc[4][4];
  const f32x4 zero = {0.0f, 0.0f, 0.0f, 0.0f};
#pragma unroll
  for (int i = 0; i < 4; ++i)
#pragma unroll
    for (int j = 0; j < 4; ++j) acc[i][j] = zero;
  mfma_core<PASSES>(s, Ah + z * aStride, (PASSES == 3) ? Al + z * aStride : Al,
                    Bh + z * bStride, (PASSES == 3) ? Bl + z * bStride : Bl,
                    lda, ldb, Kdim, blockIdx.y * 128, blockIdx.x * 128, acc);
  float* Cz = C + z * cStride;
  const int lane = threadIdx.x & 63;
  const int wave = threadIdx.x >> 6;
  const int quad = lane >> 4, l15 = lane & 15;
  const int em = (int)blockIdx.y * 128 + (wave >> 1) * 64 + quad * 4;
  const int en = (int)blockIdx.x * 128 + (wave & 1) * 64 + l15;
#pragma unroll
  for (int i = 0; i < 4; ++i)
#pragma unroll
    for (int r = 0; r < 4; ++r) {
      size_t row = (size_t)(em + i * 16 + r) * ldc;
#pragma unroll
      for (int j = 0; j < 4; ++j) Cz[row + en + j * 16] = acc[i][j][r];
    }
}

// QKV (fp16): blockIdx.x = (z<<2)|ntile (12 consecutive blocks share x rows).
// z=0 Q, z=1 K: 3-pass (x hi/lo · W hi/lo, ~fp32 accurate), out single fp16.
// z=2 V: 1-pass (rounding dominates anyway), out transposed fp16 Vt[e][m].
__global__ __launch_bounds__(256, 2) void gemm_qkv3(
    const u16* __restrict__ xh, const u16* __restrict__ xl,
    const u16* __restrict__ Wqh, const u16* __restrict__ Wql,
    const u16* __restrict__ Wkh, const u16* __restrict__ Wkl,
    const u16* __restrict__ Wvh, const float* __restrict__ bq,
    const float* __restrict__ bk, const float* __restrict__ bv,
    u16* __restrict__ Q, u16* __restrict__ K, u16* __restrict__ Vt, int ldvt) {
  __shared__ u16 s[16384];
  const int z = blockIdx.x >> 2;
  const int n0 = (blockIdx.x & 3) * 128;
  const int m0 = blockIdx.y * 128;
  f32x4 acc[4][4];
  const f32x4 zero = {0.0f, 0.0f, 0.0f, 0.0f};
#pragma unroll
  for (int i = 0; i < 4; ++i)
#pragma unroll
    for (int j = 0; j < 4; ++j) acc[i][j] = zero;

  if (z == 2) {
    mfma_core<1>(s, xh, nullptr, Wvh, nullptr, 512, 512, 512, m0, n0, acc);
  } else if (z == 1) {
    mfma_core<3>(s, xh, xl, Wkh, Wkl, 512, 512, 512, m0, n0, acc);
  } else {
    mfma_core<3>(s, xh, xl, Wqh, Wql, 512, 512, 512, m0, n0, acc);
  }

  const float* bias = (z == 0) ? bq : (z == 1) ? bk : bv;
  const int lane = threadIdx.x & 63;
  const int wave = threadIdx.x >> 6;
  const int quad = lane >> 4, l15 = lane & 15;
  const int em = m0 + (wave >> 1) * 64 + quad * 4;
  const int en = n0 + (wave & 1) * 64 + l15;
  float bj[4];
#pragma unroll
  for (int j = 0; j < 4; ++j) bj[j] = bias[en + j * 16];
  if (z < 2) {
    u16* O = (z == 0) ? Q : K;
#pragma unroll
    for (int i = 0; i < 4; ++i)
#pragma unroll
      for (int r = 0; r < 4; ++r) {
        size_t row = (size_t)(em + i * 16 + r) * 512;
#pragma unroll
        for (int j = 0; j < 4; ++j)
          O[row + en + j * 16] = f2h(acc[i][j][r] + bj[j]);
      }
  } else {
#pragma unroll
    for (int i = 0; i < 4; ++i)
#pragma unroll
      for (int r = 0; r < 4; ++r) {
        int m = em + i * 16 + r;
#pragma unroll
        for (int j = 0; j < 4; ++j)
          Vt[(size_t)(en + j * 16) * ldvt + m] = f2h(acc[i][j][r] + bj[j]);
      }
  }
}

// ------- softmax row 2048, IN-PLACE: fp32 row -> fp16 P in row's first half.
__global__ __launch_bounds__(256) void softmax_inplace(float* __restrict__ S) {
  __shared__ float red[8];
  const int tid = threadIdx.x;
  const size_t row = blockIdx.x;
  const float4* src = (const float4*)(S + row * 2048);
  float4 v0 = src[2 * tid], v1 = src[2 * tid + 1];

  float mx = fmaxf(fmaxf(fmaxf(v0.x, v0.y), fmaxf(v0.z, v0.w)),
                   fmaxf(fmaxf(v1.x, v1.y), fmaxf(v1.z, v1.w)));
#pragma unroll
  for (int off = 32; off >= 1; off >>= 1) mx = fmaxf(mx, __shfl_xor(mx, off));
  const int wid = tid >> 6, lane = tid & 63;
  if (lane == 0) red[wid] = mx;
  __syncthreads();
  if (tid == 0) red[4] = fmaxf(fmaxf(red[0], red[1]), fmaxf(red[2], red[3]));
  __syncthreads();
  mx = red[4];

  v0.x = __expf(v0.x - mx); v0.y = __expf(v0.y - mx);
  v0.z = __expf(v0.z - mx); v0.w = __expf(v0.w - mx);
  v1.x = __expf(v1.x - mx); v1.y = __expf(v1.y - mx);
  v1.z = __expf(v1.z - mx); v1.w = __expf(v1.w - mx);

  float sm = v0.x + v0.y + v0.z + v0.w + v1.x + v1.y + v1.z + v1.w;
#pragma unroll
  for (int off = 32; off >= 1; off >>= 1) sm += __shfl_xor(sm, off);
  __syncthreads();
  if (lane == 0) red[wid] = sm;
  __syncthreads();
  if (tid == 0) red[5] = red[0] + red[1] + red[2] + red[3];
  __syncthreads();
  const float inv = 1.0f / red[5];

  u16x8 o;
  o[0] = f2h(v0.x * inv); o[1] = f2h(v0.y * inv);
  o[2] = f2h(v0.z * inv); o[3] = f2h(v0.w * inv);
  o[4] = f2h(v1.x * inv); o[5] = f2h(v1.y * inv);
  o[6] = f2h(v1.z * inv); o[7] = f2h(v1.w * inv);
  *(u16x8*)((u16*)S + row * 4096 + tid * 8) = o;
}

// ================= fp32 fallback (round-0, proven; used only if ws tiny) ====
#define LTILE_M 64
#define LTILE_N 64
#define LTILE_K 32
template <bool B_NT, bool HAS_BIAS>
__device__ __forceinline__ void gemm_body_leg(const float* __restrict__ A,
                                              const float* __restrict__ Bm,
                                              const float* __restrict__ bias,
                                              float* __restrict__ C, int lda,
                                              int ldb, int ldc, int Kdim) {
  __shared__ float As[LTILE_K][LTILE_M + 4];
  __shared__ float Bs[LTILE_K][LTILE_N + 4];
  const int tid = threadIdx.x;
  const int tx = tid & 15, ty = tid >> 4;
  const int m0 = blockIdx.y * LTILE_M, n0 = blockIdx.x * LTILE_N;
  const int am = tid >> 3, ak = (tid & 7) << 2;
  const int bk_ = tid >> 4, bn = (tid & 15) << 2;
  float acc[4][4] = {};
  for (int k0 = 0; k0 < Kdim; k0 += LTILE_K) {
    float4 a0 = *(const float4*)(A + (size_t)(m0 + am) * lda + k0 + ak);
    float4 a1 = *(const float4*)(A + (size_t)(m0 + am + 32) * lda + k0 + ak);
    float4 b0, b1;
    if (B_NT) {
      b0 = *(const float4*)(Bm + (size_t)(n0 + am) * ldb + k0 + ak);
      b1 = *(const float4*)(Bm + (size_t)(n0 + am + 32) * ldb + k0 + ak);
    } else {
      b0 = *(const float4*)(Bm + (size_t)(k0 + bk_) * ldb + n0 + bn);
      b1 = *(const float4*)(Bm + (size_t)(k0 + bk_ + 16) * ldb + n0 + bn);
    }
    __syncthreads();
    As[ak + 0][am] = a0.x; As[ak + 1][am] = a0.y;
    As[ak + 2][am] = a0.z; As[ak + 3][am] = a0.w;
    As[ak + 0][am + 32] = a1.x; As[ak + 1][am + 32] = a1.y;
    As[ak + 2][am + 32] = a1.z; As[ak + 3][am + 32] = a1.w;
    if (B_NT) {
      Bs[ak + 0][am] = b0.x; Bs[ak + 1][am] = b0.y;
      Bs[ak + 2][am] = b0.z; Bs[ak + 3][am] = b0.w;
      Bs[ak + 0][am + 32] = b1.x; Bs[ak + 1][am + 32] = b1.y;
      Bs[ak + 2][am + 32] = b1.z; Bs[ak + 3][am + 32] = b1.w;
    } else {
      *(float4*)&Bs[bk_][bn] = b0;
      *(float4*)&Bs[bk_ + 16][bn] = b1;
    }
    __syncthreads();
#pragma unroll
    for (int kk = 0; kk < LTILE_K; ++kk) {
      float4 av = *(const float4*)&As[kk][ty << 2];
      float4 bv4 = *(const float4*)&Bs[kk][tx << 2];
      acc[0][0] += av.x * bv4.x; acc[0][1] += av.x * bv4.y;
      acc[0][2] += av.x * bv4.z; acc[0][3] += av.x * bv4.w;
      acc[1][0] += av.y * bv4.x; acc[1][1] += av.y * bv4.y;
      acc[1][2] += av.y * bv4.z; acc[1][3] += av.y * bv4.w;
      acc[2][0] += av.z * bv4.x; acc[2][1] += av.z * bv4.y;
      acc[2][2] += av.z * bv4.z; acc[2][3] += av.z * bv4.w;
      acc[3][0] += av.w * bv4.x; acc[3][1] += av.w * bv4.y;
      acc[3][2] += av.w * bv4.z; acc[3][3] += av.w * bv4.w;
    }
  }
  float4 badd = {0.0f, 0.0f, 0.0f, 0.0f};
  if (HAS_BIAS) badd = *(const float4*)(bias + n0 + (tx << 2));
#pragma unroll
  for (int r = 0; r < 4; ++r) {
    float4 o;
    o.x = acc[r][0] + badd.x; o.y = acc[r][1] + badd.y;
    o.z = acc[r][2] + badd.z; o.w = acc[r][3] + badd.w;
    *(float4*)(C + (size_t)(m0 + (ty << 2) + r) * ldc + n0 + (tx << 2)) = o;
  }
}
template <bool B_NT, bool HAS_BIAS>
__global__ __launch_bounds__(256, 4) void gemm_leg(const float* A, const float* Bm,
                                                   const float* bias, float* C,
                                                   int lda, int ldb, int ldc,
                                                   int Kdim) {
  gemm_body_leg<B_NT, HAS_BIAS>(A, Bm, bias, C, lda, ldb, ldc, Kdim);
}
__global__ __launch_bounds__(256, 4) void qkv_leg(
    const float* x, const float* Wq, const float* bq, const float* Wk,
    const float* bk, const float* Wv, const float* bv, float* Q, float* K,
    float* V) {
  const float *W, *bias;
  float* C;
  if (blockIdx.z == 0) { W = Wq; bias = bq; C = Q; }
  else if (blockIdx.z == 1) { W = Wk; bias = bk; C = K; }
  else { W = Wv; bias = bv; C = V; }
  gemm_body_leg<true, true>(x, W, bias, C, 512, 512, 512, 512);
}
__global__ __launch_bounds__(256) void softmax_leg(float* S, int ncols) {
  __shared__ float red[8];
  float4* rowp = (float4*)(S + (size_t)blockIdx.x * ncols);
  const int tid = threadIdx.x;
  float4 v0 = rowp[tid], v1 = rowp[tid + 256];
  float mx = fmaxf(fmaxf(fmaxf(v0.x, v0.y), fmaxf(v0.z, v0.w)),
                   fmaxf(fmaxf(v1.x, v1.y), fmaxf(v1.z, v1.w)));
#pragma unroll
  for (int off = 32; off >= 1; off >>= 1) mx = fmaxf(mx, __shfl_xor(mx, off));
  const int wid = tid >> 6, lane = tid & 63;
  if (lane == 0) red[wid] = mx;
  __syncthreads();
  if (tid == 0) red[4] = fmaxf(fmaxf(red[0], red[1]), fmaxf(red[2], red[3]));
  __syncthreads();
  mx = red[4];
  v0.x = __expf(v0.x - mx); v0.y = __expf(v0.y - mx);
  v0.z = __expf(v0.z - mx); v0.w = __expf(v0.w - mx);
  v1.x = __expf(v1.x - mx); v1.y = __expf(v1.y - mx);
  v1.w = __expf(v1.w - mx); v1.z = __expf(v1.z - mx);
  float sm = v0.x + v0.y + v0.z + v0.w + v1.x + v1.y + v1.z + v1.w;
#pragma unroll
  for (int off = 32; off >= 1; off >>= 1) sm += __shfl_xor(sm, off);
  __syncthreads();
  if (lane == 0) red[wid] = sm;
  __syncthreads();
  if (tid == 0) red[5] = red[0] + red[1] + red[2] + red[3];
  __syncthreads();
  const float inv = 1.0f / red[5];
  v0.x *= inv; v0.y *= inv; v0.z *= inv; v0.w *= inv;
  v1.x *= inv; v1.y *= inv; v1.z *= inv; v1.w *= inv;
  rowp[tid] = v0;
  rowp[tid + 256] = v1;
}

// ================================ host ================================
extern "C" void kernel_launch(void* const* d_in, const int* in_sizes, int n_in,
                              void* d_out, int out_size, void* d_ws,
                              size_t ws_size, hipStream_t stream) {
  (void)in_sizes; (void)n_in; (void)out_size;
  const int B = 8, N = 2048, D = 512;
  const size_t ND = (size_t)N * D;    // 1,048,576
  const size_t NN = (size_t)N * N;    // 4,194,304
  const float* x = (const float*)d_in[0];
  const float* Wf[3] = {(const float*)d_in[1], (const float*)d_in[3],
                        (const float*)d_in[5]};
  const float* bq = (const float*)d_in[2];
  const float* bk = (const float*)d_in[4];
  const float* bv = (const float*)d_in[6];
  float* out = (float*)d_out;

  char* w = (char*)d_ws;
  auto take = [&](size_t bytes) {
    char* p = w;
    w += (bytes + 255) & ~(size_t)255;
    return p;
  };

  if (ws_size >= 190000000ULL) {
    // ---- fp16 pipeline, fully batched (~188 MB). P written in place over S;
    // x hi/lo overlapped into S's start (dead after QKV).
    u16 *Wh[3], *Wl[3];
    for (int i = 0; i < 3; ++i) {
      Wh[i] = (u16*)take(524288);
      Wl[i] = (u16*)take(524288);
    }
    u16* Q  = (u16*)take(2 * B * ND);  // 16.78 MB each
    u16* K  = (u16*)take(2 * B * ND);
    u16* Vt = (u16*)take(2 * B * ND);
    float* S = (float*)w;              // 134.2 MB region
    u16* xh = (u16*)take(2 * B * ND);  // inside S, dead after QKV
    u16* xl = (u16*)take(2 * B * ND);

    split_h<true><<<4096, 256, 0, stream>>>(x, xh, xl, (int)(B * ND / 8));
    for (int i = 0; i < 3; ++i)
      split_h<true><<<128, 256, 0, stream>>>(Wf[i], Wh[i], Wl[i], 32768);
    gemm_qkv3<<<dim3(12, 128), 256, 0, stream>>>(
        xh, xl, Wh[0], Wl[0], Wh[1], Wl[1], Wh[2], bq, bk, bv, Q, K, Vt,
        B * N);
    // scores: 1-pass fp16, one dispatch for all batches
    gemm_f32k<1><<<dim3(16, 16, 8), 256, 0, stream>>>(
        Q, nullptr, K, nullptr, S, 512, 512, 2048, 512, ND, ND, NN);
    // softmax: in-place fp16 P (row stride 4096 u16)
    softmax_inplace<<<B * N, 256, 0, stream>>>(S);
    // PV: A = P fp16 (lda 4096, batch stride 2*NN u16), B = Vt
    gemm_f32k<1><<<dim3(4, 16, 8), 256, 0, stream>>>(
        (const u16*)S, nullptr, Vt, nullptr, out, 4096, B * N, 512, 2048,
        2 * NN, (size_t)N, ND);
  } else {
    // ---- fp32 fallback (round-0 path, 29.4 MB) ----
    float* ws = (float*)d_ws;
    float* Q = ws;
    float* Kp = ws + ND;
    float* V = ws + 2 * ND;
    float* S = ws + 3 * ND;
    for (int b = 0; b < B; ++b) {
      const float* xb = x + b * ND;
      float* outb = out + b * ND;
      qkv_leg<<<dim3(8, 32, 3), 256, 0, stream>>>(xb, Wf[0], bq, Wf[1], bk,
                                                  Wf[2], bv, Q, Kp, V);
      gemm_leg<true, false><<<dim3(32, 32), 256, 0, stream>>>(Q, Kp, nullptr, S,
                                                              512, 512, 2048, 512);
      softmax_leg<<<N, 256, 0, stream>>>(S, N);
      gemm_leg<false, false><<<dim3(8, 32), 256, 0, stream>>>(S, V, nullptr,
                                                              outb, 2048, 512,
                                                              512, 2048);
    }
  }
}

// Round 6
// 324.543 us; speedup vs baseline: 5.5980x; 1.0033x over previous
//
#include <hip/hip_runtime.h>

typedef __attribute__((ext_vector_type(8))) _Float16 f16x8;        // 8 fp16 (4 VGPRs)
typedef __attribute__((ext_vector_type(8))) unsigned short u16x8;  // 16B chunk
typedef __attribute__((ext_vector_type(4))) float f32x4;
typedef unsigned short u16;

__device__ __forceinline__ u16 f2h(float f) {  // RNE fp16
  _Float16 h = (_Float16)f;
  return __builtin_bit_cast(u16, h);
}
__device__ __forceinline__ float h2f(u16 u) {
  return (float)__builtin_bit_cast(_Float16, u);
}

// Async global->LDS DMA, 16B per lane (dest = wave-uniform base + lane*16).
__device__ __forceinline__ void gl_lds16(const u16* g, u16* l) {
  __builtin_amdgcn_global_load_lds(
      (const __attribute__((address_space(1))) void*)g,
      (__attribute__((address_space(3))) void*)l, 16, 0, 0);
}

// ---------------- fp32 -> fp16 convert (hi only) ----------------
__global__ __launch_bounds__(256) void cvt_h(const float* __restrict__ in,
                                             u16* __restrict__ hi, int n8) {
  int t = blockIdx.x * 256 + threadIdx.x;
  if (t >= n8) return;
  const float4* p = (const float4*)in;
  float4 a = p[2 * t], b = p[2 * t + 1];
  float v[8] = {a.x, a.y, a.z, a.w, b.x, b.y, b.z, b.w};
  u16x8 h;
#pragma unroll
  for (int i = 0; i < 8; ++i) h[i] = f2h(v[i]);
  *(u16x8*)(hi + (size_t)t * 8) = h;
}

// ---------------- MFMA GEMM core (fp16, global_load_lds staging) ----------
// C[m,n] = sum_k A[m,k]*B[n,k], operands row-major [free][k] fp16.
// BM=BN=128, BK=32, 256 threads (4 waves), 64x64/wave via 4x4 mfma 16x16x32.
// LDS per matrix: [row 0..127][32 u16] unpadded (8 KB), 2 DMA-dwordx4 per
// wave per matrix per k-step.
__device__ __forceinline__ void mfma_core1(u16* s, const u16* __restrict__ A,
                                           const u16* __restrict__ B,
                                           int lda, int ldb, int Kdim,
                                           int m0, int n0, f32x4 acc[4][4]) {
  const int tid = threadIdx.x;
  const int l = tid & 63, w = tid >> 6;
  const int wm = w >> 1, wn = w & 1;
  const int quad = l >> 4, l15 = l & 15;
  const int srow = w * 32 + (l >> 2);  // staging row (and +16)
  const int skc = (l & 3) * 8;         // staging k offset (u16)

  u16* sA = s;
  u16* sB = s + 4096;

  const u16* gA0 = A + (size_t)(m0 + srow) * lda + skc;
  const u16* gB0 = B + (size_t)(n0 + srow) * ldb + skc;
  u16* lA0 = sA + srow * 32 + skc;
  u16* lB0 = sB + srow * 32 + skc;
  const size_t a16 = (size_t)16 * lda, b16 = (size_t)16 * ldb;

  const int afrag = (wm * 64 + l15) * 32 + quad * 8;  // u16 idx; +i*512 rows
  const int bfrag = (wn * 64 + l15) * 32 + quad * 8;

  for (int k0 = 0; k0 < Kdim; k0 += 32) {
    __syncthreads();  // previous tile's ds_reads done before DMA overwrite
    gl_lds16(gA0 + k0, lA0);
    gl_lds16(gA0 + k0 + a16, lA0 + 512);
    gl_lds16(gB0 + k0, lB0);
    gl_lds16(gB0 + k0 + b16, lB0 + 512);
    __syncthreads();  // drains vmcnt (DMA visible)

    f16x8 fa[4], fb[4];
#pragma unroll
    for (int i = 0; i < 4; ++i) fa[i] = *(const f16x8*)(sA + afrag + i * 512);
#pragma unroll
    for (int j = 0; j < 4; ++j) fb[j] = *(const f16x8*)(sB + bfrag + j * 512);
#pragma unroll
    for (int i = 0; i < 4; ++i)
#pragma unroll
      for (int j = 0; j < 4; ++j)
        acc[i][j] = __builtin_amdgcn_mfma_f32_16x16x32_f16(fa[i], fb[j],
                                                           acc[i][j], 0, 0, 0);
  }
}

// C/D layout (m89-verified): row m = quad*4 + reg, col n = lane&15.
__global__ __launch_bounds__(256, 2) void gemm_f32o(
    const u16* __restrict__ A, const u16* __restrict__ B, float* __restrict__ C,
    int lda, int ldb, int ldc, int Kdim, size_t aStride, size_t bStride,
    size_t cStride) {
  __shared__ u16 s[8192];
  const int z = blockIdx.z;
  f32x4 acc[4][4];
  const f32x4 zero = {0.0f, 0.0f, 0.0f, 0.0f};
#pragma unroll
  for (int i = 0; i < 4; ++i)
#pragma unroll
    for (int j = 0; j < 4; ++j) acc[i][j] = zero;
  mfma_core1(s, A + z * aStride, B + z * bStride, lda, ldb, Kdim,
             blockIdx.y * 128, blockIdx.x * 128, acc);
  float* Cz = C + z * cStride;
  const int lane = threadIdx.x & 63;
  const int wave = threadIdx.x >> 6;
  const int quad = lane >> 4, l15 = lane & 15;
  const int em = (int)blockIdx.y * 128 + (wave >> 1) * 64 + quad * 4;
  const int en = (int)blockIdx.x * 128 + (wave & 1) * 64 + l15;
#pragma unroll
  for (int i = 0; i < 4; ++i)
#pragma unroll
    for (int r = 0; r < 4; ++r) {
      size_t row = (size_t)(em + i * 16 + r) * ldc;
#pragma unroll
      for (int j = 0; j < 4; ++j) Cz[row + en + j * 16] = acc[i][j][r];
    }
}

// QKV (fp16, 1-pass): blockIdx.x = (z<<2)|ntile (12 consecutive blocks share
// the same x rows -> L3 temporal reuse). z=0 Q, z=1 K (row-major fp16 out),
// z=2 V (transposed fp16 out Vt[e][m]). Accuracy: Q/K are stored fp16 anyway
// (rel. 2.9e-4); 1-pass compute error ~2e-4 is below that floor.
__global__ __launch_bounds__(256, 2) void gemm_qkv4(
    const u16* __restrict__ xh, const u16* __restrict__ Wq,
    const u16* __restrict__ Wk, const u16* __restrict__ Wv,
    const float* __restrict__ bq, const float* __restrict__ bk,
    const float* __restrict__ bv, u16* __restrict__ Q, u16* __restrict__ K,
    u16* __restrict__ Vt, int ldvt) {
  __shared__ u16 s[8192];
  const int z = blockIdx.x >> 2;
  const int n0 = (blockIdx.x & 3) * 128;
  const int m0 = blockIdx.y * 128;
  const u16* W = (z == 0) ? Wq : (z == 1) ? Wk : Wv;
  const float* bias = (z == 0) ? bq : (z == 1) ? bk : bv;
  f32x4 acc[4][4];
  const f32x4 zero = {0.0f, 0.0f, 0.0f, 0.0f};
#pragma unroll
  for (int i = 0; i < 4; ++i)
#pragma unroll
    for (int j = 0; j < 4; ++j) acc[i][j] = zero;

  mfma_core1(s, xh, W, 512, 512, 512, m0, n0, acc);

  const int lane = threadIdx.x & 63;
  const int wave = threadIdx.x >> 6;
  const int quad = lane >> 4, l15 = lane & 15;
  const int em = m0 + (wave >> 1) * 64 + quad * 4;
  const int en = n0 + (wave & 1) * 64 + l15;
  float bj[4];
#pragma unroll
  for (int j = 0; j < 4; ++j) bj[j] = bias[en + j * 16];
  if (z < 2) {
    u16* O = (z == 0) ? Q : K;
#pragma unroll
    for (int i = 0; i < 4; ++i)
#pragma unroll
      for (int r = 0; r < 4; ++r) {
        size_t row = (size_t)(em + i * 16 + r) * 512;
#pragma unroll
        for (int j = 0; j < 4; ++j)
          O[row + en + j * 16] = f2h(acc[i][j][r] + bj[j]);
      }
  } else {
#pragma unroll
    for (int i = 0; i < 4; ++i)
#pragma unroll
      for (int r = 0; r < 4; ++r) {
        int m = em + i * 16 + r;
#pragma unroll
        for (int j = 0; j < 4; ++j)
          Vt[(size_t)(en + j * 16) * ldvt + m] = f2h(acc[i][j][r] + bj[j]);
      }
  }
}

// ------- softmax row 2048, IN-PLACE: fp32 row -> fp16 P in row's first half.
__global__ __launch_bounds__(256) void softmax_inplace(float* __restrict__ S) {
  __shared__ float red[8];
  const int tid = threadIdx.x;
  const size_t row = blockIdx.x;
  const float4* src = (const float4*)(S + row * 2048);
  float4 v0 = src[2 * tid], v1 = src[2 * tid + 1];

  float mx = fmaxf(fmaxf(fmaxf(v0.x, v0.y), fmaxf(v0.z, v0.w)),
                   fmaxf(fmaxf(v1.x, v1.y), fmaxf(v1.z, v1.w)));
#pragma unroll
  for (int off = 32; off >= 1; off >>= 1) mx = fmaxf(mx, __shfl_xor(mx, off));
  const int wid = tid >> 6, lane = tid & 63;
  if (lane == 0) red[wid] = mx;
  __syncthreads();
  if (tid == 0) red[4] = fmaxf(fmaxf(red[0], red[1]), fmaxf(red[2], red[3]));
  __syncthreads();
  mx = red[4];

  v0.x = __expf(v0.x - mx); v0.y = __expf(v0.y - mx);
  v0.z = __expf(v0.z - mx); v0.w = __expf(v0.w - mx);
  v1.x = __expf(v1.x - mx); v1.y = __expf(v1.y - mx);
  v1.z = __expf(v1.z - mx); v1.w = __expf(v1.w - mx);

  float sm = v0.x + v0.y + v0.z + v0.w + v1.x + v1.y + v1.z + v1.w;
#pragma unroll
  for (int off = 32; off >= 1; off >>= 1) sm += __shfl_xor(sm, off);
  __syncthreads();
  if (lane == 0) red[wid] = sm;
  __syncthreads();
  if (tid == 0) red[5] = red[0] + red[1] + red[2] + red[3];
  __syncthreads();
  const float inv = 1.0f / red[5];

  u16x8 o;
  o[0] = f2h(v0.x * inv); o[1] = f2h(v0.y * inv);
  o[2] = f2h(v0.z * inv); o[3] = f2h(v0.w * inv);
  o[4] = f2h(v1.x * inv); o[5] = f2h(v1.y * inv);
  o[6] = f2h(v1.z * inv); o[7] = f2h(v1.w * inv);
  *(u16x8*)((u16*)S + row * 4096 + tid * 8) = o;
}

// ================= fp32 fallback (round-0, proven; used only if ws tiny) ====
#define LTILE_M 64
#define LTILE_N 64
#define LTILE_K 32
template <bool B_NT, bool HAS_BIAS>
__device__ __forceinline__ void gemm_body_leg(const float* __restrict__ A,
                                              const float* __restrict__ Bm,
                                              const float* __restrict__ bias,
                                              float* __restrict__ C, int lda,
                                              int ldb, int ldc, int Kdim) {
  __shared__ float As[LTILE_K][LTILE_M + 4];
  __shared__ float Bs[LTILE_K][LTILE_N + 4];
  const int tid = threadIdx.x;
  const int tx = tid & 15, ty = tid >> 4;
  const int m0 = blockIdx.y * LTILE_M, n0 = blockIdx.x * LTILE_N;
  const int am = tid >> 3, ak = (tid & 7) << 2;
  const int bk_ = tid >> 4, bn = (tid & 15) << 2;
  float acc[4][4] = {};
  for (int k0 = 0; k0 < Kdim; k0 += LTILE_K) {
    float4 a0 = *(const float4*)(A + (size_t)(m0 + am) * lda + k0 + ak);
    float4 a1 = *(const float4*)(A + (size_t)(m0 + am + 32) * lda + k0 + ak);
    float4 b0, b1;
    if (B_NT) {
      b0 = *(const float4*)(Bm + (size_t)(n0 + am) * ldb + k0 + ak);
      b1 = *(const float4*)(Bm + (size_t)(n0 + am + 32) * ldb + k0 + ak);
    } else {
      b0 = *(const float4*)(Bm + (size_t)(k0 + bk_) * ldb + n0 + bn);
      b1 = *(const float4*)(Bm + (size_t)(k0 + bk_ + 16) * ldb + n0 + bn);
    }
    __syncthreads();
    As[ak + 0][am] = a0.x; As[ak + 1][am] = a0.y;
    As[ak + 2][am] = a0.z; As[ak + 3][am] = a0.w;
    As[ak + 0][am + 32] = a1.x; As[ak + 1][am + 32] = a1.y;
    As[ak + 2][am + 32] = a1.z; As[ak + 3][am + 32] = a1.w;
    if (B_NT) {
      Bs[ak + 0][am] = b0.x; Bs[ak + 1][am] = b0.y;
      Bs[ak + 2][am] = b0.z; Bs[ak + 3][am] = b0.w;
      Bs[ak + 0][am + 32] = b1.x; Bs[ak + 1][am + 32] = b1.y;
      Bs[ak + 2][am + 32] = b1.z; Bs[ak + 3][am + 32] = b1.w;
    } else {
      *(float4*)&Bs[bk_][bn] = b0;
      *(float4*)&Bs[bk_ + 16][bn] = b1;
    }
    __syncthreads();
#pragma unroll
    for (int kk = 0; kk < LTILE_K; ++kk) {
      float4 av = *(const float4*)&As[kk][ty << 2];
      float4 bv4 = *(const float4*)&Bs[kk][tx << 2];
      acc[0][0] += av.x * bv4.x; acc[0][1] += av.x * bv4.y;
      acc[0][2] += av.x * bv4.z; acc[0][3] += av.x * bv4.w;
      acc[1][0] += av.y * bv4.x; acc[1][1] += av.y * bv4.y;
      acc[1][2] += av.y * bv4.z; acc[1][3] += av.y * bv4.w;
      acc[2][0] += av.z * bv4.x; acc[2][1] += av.z * bv4.y;
      acc[2][2] += av.z * bv4.z; acc[2][3] += av.z * bv4.w;
      acc[3][0] += av.w * bv4.x; acc[3][1] += av.w * bv4.y;
      acc[3][2] += av.w * bv4.z; acc[3][3] += av.w * bv4.w;
    }
  }
  float4 badd = {0.0f, 0.0f, 0.0f, 0.0f};
  if (HAS_BIAS) badd = *(const float4*)(bias + n0 + (tx << 2));
#pragma unroll
  for (int r = 0; r < 4; ++r) {
    float4 o;
    o.x = acc[r][0] + badd.x; o.y = acc[r][1] + badd.y;
    o.z = acc[r][2] + badd.z; o.w = acc[r][3] + badd.w;
    *(float4*)(C + (size_t)(m0 + (ty << 2) + r) * ldc + n0 + (tx << 2)) = o;
  }
}
template <bool B_NT, bool HAS_BIAS>
__global__ __launch_bounds__(256, 4) void gemm_leg(const float* A, const float* Bm,
                                                   const float* bias, float* C,
                                                   int lda, int ldb, int ldc,
                                                   int Kdim) {
  gemm_body_leg<B_NT, HAS_BIAS>(A, Bm, bias, C, lda, ldb, ldc, Kdim);
}
__global__ __launch_bounds__(256, 4) void qkv_leg(
    const float* x, const float* Wq, const float* bq, const float* Wk,
    const float* bk, const float* Wv, const float* bv, float* Q, float* K,
    float* V) {
  const float *W, *bias;
  float* C;
  if (blockIdx.z == 0) { W = Wq; bias = bq; C = Q; }
  else if (blockIdx.z == 1) { W = Wk; bias = bk; C = K; }
  else { W = Wv; bias = bv; C = V; }
  gemm_body_leg<true, true>(x, W, bias, C, 512, 512, 512, 512);
}
__global__ __launch_bounds__(256) void softmax_leg(float* S, int ncols) {
  __shared__ float red[8];
  float4* rowp = (float4*)(S + (size_t)blockIdx.x * ncols);
  const int tid = threadIdx.x;
  float4 v0 = rowp[tid], v1 = rowp[tid + 256];
  float mx = fmaxf(fmaxf(fmaxf(v0.x, v0.y), fmaxf(v0.z, v0.w)),
                   fmaxf(fmaxf(v1.x, v1.y), fmaxf(v1.z, v1.w)));
#pragma unroll
  for (int off = 32; off >= 1; off >>= 1) mx = fmaxf(mx, __shfl_xor(mx, off));
  const int wid = tid >> 6, lane = tid & 63;
  if (lane == 0) red[wid] = mx;
  __syncthreads();
  if (tid == 0) red[4] = fmaxf(fmaxf(red[0], red[1]), fmaxf(red[2], red[3]));
  __syncthreads();
  mx = red[4];
  v0.x = __expf(v0.x - mx); v0.y = __expf(v0.y - mx);
  v0.z = __expf(v0.z - mx); v0.w = __expf(v0.w - mx);
  v1.x = __expf(v1.x - mx); v1.y = __expf(v1.y - mx);
  v1.w = __expf(v1.w - mx); v1.z = __expf(v1.z - mx);
  float sm = v0.x + v0.y + v0.z + v0.w + v1.x + v1.y + v1.z + v1.w;
#pragma unroll
  for (int off = 32; off >= 1; off >>= 1) sm += __shfl_xor(sm, off);
  __syncthreads();
  if (lane == 0) red[wid] = sm;
  __syncthreads();
  if (tid == 0) red[5] = red[0] + red[1] + red[2] + red[3];
  __syncthreads();
  const float inv = 1.0f / red[5];
  v0.x *= inv; v0.y *= inv; v0.z *= inv; v0.w *= inv;
  v1.x *= inv; v1.y *= inv; v1.z *= inv; v1.w *= inv;
  rowp[tid] = v0;
  rowp[tid + 256] = v1;
}

// ================================ host ================================
extern "C" void kernel_launch(void* const* d_in, const int* in_sizes, int n_in,
                              void* d_out, int out_size, void* d_ws,
                              size_t ws_size, hipStream_t stream) {
  (void)in_sizes; (void)n_in; (void)out_size;
  const int B = 8, N = 2048, D = 512;
  const size_t ND = (size_t)N * D;    // 1,048,576
  const size_t NN = (size_t)N * N;    // 4,194,304
  const float* x = (const float*)d_in[0];
  const float* Wf[3] = {(const float*)d_in[1], (const float*)d_in[3],
                        (const float*)d_in[5]};
  const float* bq = (const float*)d_in[2];
  const float* bk = (const float*)d_in[4];
  const float* bv = (const float*)d_in[6];
  float* out = (float*)d_out;

  char* w = (char*)d_ws;
  auto take = [&](size_t bytes) {
    char* p = w;
    w += (bytes + 255) & ~(size_t)255;
    return p;
  };

  if (ws_size >= 190000000ULL) {
    // ---- fp16 pipeline, fully batched (~186 MB), all GEMMs 1-pass.
    // P written in place over S; x fp16 overlapped into S (dead after QKV).
    u16* Wh[3];
    for (int i = 0; i < 3; ++i) Wh[i] = (u16*)take(524288);
    u16* Q  = (u16*)take(2 * B * ND);  // 16.78 MB each
    u16* K  = (u16*)take(2 * B * ND);
    u16* Vt = (u16*)take(2 * B * ND);
    float* S = (float*)w;              // 134.2 MB region
    u16* xh = (u16*)take(2 * B * ND);  // inside S, dead after QKV

    cvt_h<<<8192, 256, 0, stream>>>(x, xh, (int)(B * ND / 8));
    for (int i = 0; i < 3; ++i)
      cvt_h<<<128, 256, 0, stream>>>(Wf[i], Wh[i], 32768);
    gemm_qkv4<<<dim3(12, 128), 256, 0, stream>>>(
        xh, Wh[0], Wh[1], Wh[2], bq, bk, bv, Q, K, Vt, B * N);
    // scores: 1-pass fp16, one dispatch for all batches
    gemm_f32o<<<dim3(16, 16, 8), 256, 0, stream>>>(
        Q, K, S, 512, 512, 2048, 512, ND, ND, NN);
    // softmax: in-place fp16 P (row stride 4096 u16)
    softmax_inplace<<<B * N, 256, 0, stream>>>(S);
    // PV: A = P fp16 (lda 4096, batch stride 2*NN u16), B = Vt
    gemm_f32o<<<dim3(4, 16, 8), 256, 0, stream>>>(
        (const u16*)S, Vt, out, 4096, B * N, 512, 2048, 2 * NN, (size_t)N, ND);
  } else {
    // ---- fp32 fallback (round-0 path, 29.4 MB) ----
    float* ws = (float*)d_ws;
    float* Q = ws;
    float* Kp = ws + ND;
    float* V = ws + 2 * ND;
    float* S = ws + 3 * ND;
    for (int b = 0; b < B; ++b) {
      const float* xb = x + b * ND;
      float* outb = out + b * ND;
      qkv_leg<<<dim3(8, 32, 3), 256, 0, stream>>>(xb, Wf[0], bq, Wf[1], bk,
                                                  Wf[2], bv, Q, Kp, V);
      gemm_leg<true, false><<<dim3(32, 32), 256, 0, stream>>>(Q, Kp, nullptr, S,
                                                              512, 512, 2048, 512);
      softmax_leg<<<N, 256, 0, stream>>>(S, N);
      gemm_leg<false, false><<<dim3(8, 32), 256, 0, stream>>>(S, V, nullptr,
                                                              outb, 2048, 512,
                                                              512, 2048);
    }
  }
}